// Round 4
// baseline (1326.742 us; speedup 1.0000x reference)
//
#include <hip/hip_runtime.h>
#include <math.h>

typedef unsigned short ushort_t;
typedef unsigned int uint32;
typedef __attribute__((ext_vector_type(8))) short v8s;
typedef __attribute__((ext_vector_type(4))) float v4f;

#define B_ 2
#define T_ 4096
#define DIM_ 512
#define H_ 8
#define DH_ 64
#define BH_ 16
#define NHASH_ 8
#define NB_ 64
#define NCH_ 512
#define FF_ 2048
#define TAGS_ 17
#define ROWS_ 8192
#define SORTN_ 32768
#define QV_N 1024

__device__ __forceinline__ float bf2f(ushort_t u){
  return __uint_as_float(((uint32)u) << 16);
}
__device__ __forceinline__ ushort_t f2bf(float f){
  uint32 u = __float_as_uint(f);
  u += 0x7fffu + ((u >> 16) & 1u);
  return (ushort_t)(u >> 16);
}
__device__ __forceinline__ void split2(float a, ushort_t& h, ushort_t& l){
  h = f2bf(a);
  l = f2bf(a - bf2f(h));
}
// async global->LDS, 16B per lane; LDS dest = base + lane*16 (wave-uniform base)
__device__ __forceinline__ void gl16(const ushort_t* g, ushort_t* l){
  __builtin_amdgcn_global_load_lds(
      (const __attribute__((address_space(1))) unsigned int*)g,
      (__attribute__((address_space(3))) unsigned int*)l, 16, 0, 0);
}

// ---------------- embed
__global__ __launch_bounds__(256) void k_embed(const int* __restrict__ X,
                                               const float* __restrict__ tok,
                                               const float* __restrict__ ax1,
                                               const float* __restrict__ ax2,
                                               float* __restrict__ x1, float* __restrict__ x2){
  int row = blockIdx.x;
  int t = row & (T_-1);
  int tokid = X[row];
  size_t base = (size_t)row * DIM_;
  for (int d = threadIdx.x; d < DIM_; d += 256){
    float e = tok[(size_t)tokid*DIM_ + d];
    float p = (d < 256) ? ax1[(t>>6)*256 + d] : ax2[(t&63)*256 + (d-256)];
    float v = e + p;
    x1[base+d] = v; x2[base+d] = v;
  }
}

// ---------------- layernorm; writes fp32 (Yf) or split planes (Yh/Yl)
__global__ __launch_bounds__(256) void k_ln(const float* __restrict__ A, const float* __restrict__ Bb,
                                            const float* __restrict__ g, const float* __restrict__ be,
                                            float* __restrict__ Yf,
                                            ushort_t* __restrict__ Yh, ushort_t* __restrict__ Yl){
  int row = blockIdx.x; int tid = threadIdx.x;
  size_t base = (size_t)row * DIM_;
  float x0 = A[base+tid], x1v = A[base+tid+256];
  if (Bb){ x0 = 0.5f*(x0 + Bb[base+tid]); x1v = 0.5f*(x1v + Bb[base+tid+256]); }
  float s = x0 + x1v, sq = x0*x0 + x1v*x1v;
  for (int o=32;o>0;o>>=1){ s += __shfl_down(s,o); sq += __shfl_down(sq,o); }
  __shared__ float ls[4], lq[4], mm[2];
  if ((tid&63)==0){ ls[tid>>6]=s; lq[tid>>6]=sq; }
  __syncthreads();
  if (tid==0){
    float S=ls[0]+ls[1]+ls[2]+ls[3], Q=lq[0]+lq[1]+lq[2]+lq[3];
    float m = S*(1.0f/DIM_); float var = Q*(1.0f/DIM_) - m*m;
    mm[0]=m; mm[1]=1.0f/sqrtf(var+1e-5f);
  }
  __syncthreads();
  float m=mm[0], r=mm[1];
  float y0 = (x0 -m)*r*g[tid]     + be[tid];
  float y1 = (x1v-m)*r*g[tid+256] + be[tid+256];
  if (Yf){
    Yf[base+tid] = y0; Yf[base+tid+256] = y1;
  } else {
    ushort_t h, l;
    split2(y0, h, l); Yh[base+tid] = h;     Yl[base+tid] = l;
    split2(y1, h, l); Yh[base+tid+256] = h; Yl[base+tid+256] = l;
  }
}

// ---------------- weight pre-split + transpose
__global__ __launch_bounds__(256) void k_splitw(const float* __restrict__ W,
                                                ushort_t* __restrict__ Whi, ushort_t* __restrict__ Wlo,
                                                int K, int N){
  __shared__ float tile[32][33];
  int n0 = blockIdx.x*32, k0 = blockIdx.y*32;
  int tid = threadIdx.x;
  for (int idx=tid; idx<1024; idx+=256){
    int kk = idx>>5, nn = idx&31;
    tile[kk][nn] = W[(size_t)(k0+kk)*N + n0+nn];
  }
  __syncthreads();
  for (int idx=tid; idx<1024; idx+=256){
    int nn = idx>>5, kk = idx&31;
    float a = tile[kk][nn];
    ushort_t h, l; split2(a, h, l);
    size_t off = (size_t)(n0+nn)*K + k0+kk;
    Whi[off] = h; Wlo[off] = l;
  }
}

// ---------------- split-bf16 MFMA GEMM, 128x128 block, BK=32,
// global_load_lds staging, unpadded stride-32 LDS.
// XCD-aware block swizzle: flat%8 selects the XCD chunk; each XCD owns a
// contiguous bm-range with ALL bn -> A-panels become L2-resident per XCD.
// NBUF=1: m97 single-buffer (2 barriers/step) — for grids with >=4 blocks/CU.
// NBUF=2: 2-DEEP counted-vmcnt pipeline (T4): loads for step k issued at
//         step k-2; wait is vmcnt(8) (newest 8 stay in flight across the
//         barrier), raw s_barrier. Drain to vmcnt(0) only on last step.
// flags: 1 = += into outF, 2 = gelu, 4 = split output planes
template<int NBUF>
__global__ __launch_bounds__(256) void k_gemm_mfma(
    const ushort_t* __restrict__ A_hi, const ushort_t* __restrict__ A_lo,
    const ushort_t* __restrict__ Bt_hi, const ushort_t* __restrict__ Bt_lo,
    const float* __restrict__ bias,
    float* __restrict__ outF,
    ushort_t* __restrict__ out_hi, ushort_t* __restrict__ out_lo,
    int M, int N, int K, int flags){
  // layout: [buf][plane][128*32]
  __shared__ ushort_t As[NBUF*2*128*32];
  __shared__ ushort_t Bs[NBUF*2*128*32];
  int tid = threadIdx.x;
  // XCD-aware swizzle (bijective when gridDim.y % 8 == 0)
  int nx = gridDim.x, ny = gridDim.y;
  int bn_i, bm_i;
  if ((ny & 7) == 0){
    int flat = blockIdx.x + nx*blockIdx.y;
    int xcd = flat & 7, j = flat >> 3;
    bn_i = j % nx;
    bm_i = xcd*(ny>>3) + j/nx;
  } else {
    bn_i = blockIdx.x; bm_i = blockIdx.y;
  }
  int bn = bn_i * 128, bm = bm_i * 128;
  int w = tid>>6, lane = tid&63;
  int wm = w>>1, wn = w&1;
  int lr = lane&15, quad = lane>>4;
  int lrow = lane>>2, lcol = (lane&3)*8;
  v4f acc[4][4];
  #pragma unroll
  for (int mt=0;mt<4;mt++)
    #pragma unroll
    for (int nt=0;nt<4;nt++) acc[mt][nt] = (v4f){0.f,0.f,0.f,0.f};

  v8s fa_h[4], fa_l[4], fb_h[4], fb_l[4];

  auto STAGE = [&](int buf, int k0){
    #pragma unroll
    for (int i=0;i<2;i++){
      int cr = i*64 + w*16 + lrow;               // tile row this lane stages
      int lb = buf*8192 + (i*64 + w*16)*32;      // wave-uniform LDS base (ushorts)
      size_t goA = (size_t)(bm+cr)*K + k0 + lcol;
      size_t goB = (size_t)(bn+cr)*K + k0 + lcol;
      gl16(A_hi + goA, &As[lb]);
      gl16(A_lo + goA, &As[lb + 4096]);
      gl16(Bt_hi + goB, &Bs[lb]);
      gl16(Bt_lo + goB, &Bs[lb + 4096]);
    }
  };
  auto LOADFRAGS = [&](int buf){
    int bo = buf*8192;
    #pragma unroll
    for (int mt=0;mt<4;mt++){
      int ro = (wm*64 + mt*16 + lr)*32 + quad*8;
      fa_h[mt] = *(const v8s*)&As[bo + ro];
      fa_l[mt] = *(const v8s*)&As[bo + 4096 + ro];
    }
    #pragma unroll
    for (int nt=0;nt<4;nt++){
      int ro = (wn*64 + nt*16 + lr)*32 + quad*8;
      fb_h[nt] = *(const v8s*)&Bs[bo + ro];
      fb_l[nt] = *(const v8s*)&Bs[bo + 4096 + ro];
    }
  };
  auto DOMFMA = [&](){
    #pragma unroll
    for (int mt=0;mt<4;mt++)
      #pragma unroll
      for (int nt=0;nt<4;nt++){
        acc[mt][nt] = __builtin_amdgcn_mfma_f32_16x16x32_bf16(fa_h[mt], fb_h[nt], acc[mt][nt], 0,0,0);
        acc[mt][nt] = __builtin_amdgcn_mfma_f32_16x16x32_bf16(fa_h[mt], fb_l[nt], acc[mt][nt], 0,0,0);
        acc[mt][nt] = __builtin_amdgcn_mfma_f32_16x16x32_bf16(fa_l[mt], fb_h[nt], acc[mt][nt], 0,0,0);
      }
  };

  if constexpr (NBUF == 2){
    // 2-deep prologue: buffers 0 and 1 in flight (8 loads/lane each)
    STAGE(0, 0);
    if (K > 32) STAGE(1, 32);
    int cur = 0;
    for (int k0=0; k0<K; k0+=32){
      // wait for buf[cur]'s 8 loads (the oldest); newer 8 stay in flight
      if (k0 + 32 < K){
        asm volatile("s_waitcnt vmcnt(8)" ::: "memory");
      } else {
        asm volatile("s_waitcnt vmcnt(0)" ::: "memory");
      }
      __builtin_amdgcn_sched_barrier(0);
      __builtin_amdgcn_s_barrier();   // every wave drained its buf[cur] writes
      LOADFRAGS(cur);
      DOMFMA();
      __builtin_amdgcn_s_barrier();   // all waves done reading buf[cur]
      if (k0 + 64 < K) STAGE(cur, k0 + 64);   // reuse buf[cur] for tile k+2
      cur ^= 1;
    }
  } else {
    for (int k0=0; k0<K; k0+=32){
      STAGE(0, k0);
      __syncthreads();
      LOADFRAGS(0);
      DOMFMA();
      __syncthreads();
    }
  }

  #pragma unroll
  for (int mt=0;mt<4;mt++){
    #pragma unroll
    for (int nt=0;nt<4;nt++){
      int col = bn + wn*64 + nt*16 + lr;
      float bv = bias ? bias[col] : 0.f;
      #pragma unroll
      for (int r=0;r<4;r++){
        int row = bm + wm*64 + mt*16 + quad*4 + r;
        float v = acc[mt][nt][r] + bv;
        if (flags & 2){
          float x = v;
          float inner = 0.7978845608028654f * (x + 0.044715f*x*x*x);
          // tanh(i) = 1 - 2/(exp(2i)+1), fast-exp form
          float t = 1.0f - 2.0f / (__expf(2.0f*inner) + 1.0f);
          v = 0.5f*x*(1.0f + t);
        }
        size_t off = (size_t)row*N + col;
        if (flags & 4){
          ushort_t h, l; split2(v, h, l);
          out_hi[off] = h; out_lo[off] = l;
        } else if (flags & 1){
          outF[off] += v;
        } else {
          outF[off] = v;
        }
      }
    }
  }
}

// ---------------- LSH bucketing from split qv planes
__global__ __launch_bounds__(256) void k_buckets(const ushort_t* __restrict__ qv_hi,
                                                 const ushort_t* __restrict__ qv_lo,
                                                 const float* __restrict__ rot,
                                                 int* __restrict__ buckets){
  __shared__ float rotS[DH_][32];
  __shared__ float qs[64][68];
  int t0 = blockIdx.x * 64;
  int h  = blockIdx.y;
  int bh = blockIdx.z;
  int b = bh >> 3, head = bh & 7;
  int tid = threadIdx.x;
  for (int idx = tid; idx < DH_*32; idx += 256){
    int d = idx >> 5, j = idx & 31;
    rotS[d][j] = rot[(size_t)d*(NHASH_*32) + h*32 + j];
  }
  for (int idx = tid; idx < 64*DH_; idx += 256){
    int tt = idx >> 6, d = idx & 63;
    size_t off = ((size_t)(b*T_ + t0 + tt))*QV_N + head*DH_ + d;
    qs[tt][d] = bf2f(qv_hi[off]) + bf2f(qv_lo[off]);
  }
  __syncthreads();
  int tt = tid >> 2, lane = tid & 3;
  int j0 = lane * 8;
  float r8[8];
  #pragma unroll
  for (int k=0;k<8;k++) r8[k] = 0.f;
  for (int d=0; d<DH_; d++){
    float q = qs[tt][d];
    #pragma unroll
    for (int k=0;k<8;k++) r8[k] += q * rotS[d][j0+k];
  }
  float best = r8[0]; int bidx = j0;
  #pragma unroll
  for (int k=1;k<8;k++){ if (r8[k] > best){ best = r8[k]; bidx = j0+k; } }
  #pragma unroll
  for (int k=0;k<8;k++){ float v = -r8[k]; if (v > best){ best = v; bidx = 32+j0+k; } }
  #pragma unroll
  for (int x=1; x<=2; x<<=1){
    float ov = __shfl_xor(best, x);
    int   oi = __shfl_xor(bidx, x);
    if (ov > best || (ov == best && oi < bidx)){ best = ov; bidx = oi; }
  }
  if (lane == 0)
    buckets[((size_t)bh*NHASH_ + h)*T_ + t0 + tt] = bidx;
}

// ---------------- stable counting sort per (bh, hash)
__global__ __launch_bounds__(256) void k_sort(const int* __restrict__ buckets,
                                              int* __restrict__ st){
  int blk = blockIdx.x;
  int bh = blk >> 3, h = blk & 7;
  const int* bptr = buckets + ((size_t)bh*NHASH_ + h)*T_;
  __shared__ unsigned char bb[T_];
  __shared__ int cnt[4][NB_];
  __shared__ int offs[NB_];
  int tid = threadIdx.x;
  for (int i = tid; i < T_; i += 256) bb[i] = (unsigned char)bptr[i];
  __syncthreads();
  int q = tid >> 6, j = tid & 63;
  int c0 = 0;
  for (int t = q*1024; t < q*1024 + 1024; t++) c0 += (bb[t]==j) ? 1 : 0;
  cnt[q][j] = c0;
  __syncthreads();
  if (tid == 0){
    int run = 0;
    for (int jj=0; jj<NB_; jj++){
      offs[jj] = run;
      run += cnt[0][jj] + cnt[1][jj] + cnt[2][jj] + cnt[3][jj];
    }
  }
  __syncthreads();
  int off = offs[j];
  for (int qq=0; qq<q; qq++) off += cnt[qq][j];
  size_t base = (size_t)bh*SORTN_ + (size_t)h*T_;
  for (int t = q*1024; t < q*1024 + 1024; t++){
    if (bb[t]==j){ st[base+off] = t; off++; }
  }
}

// ---------------- flash-MFMA LSH attention; inputs pre-split qv planes
// V^T LDS region is XOR-swizzled: element (d, j) lives at d*136 + (j ^ (d&56)).
__global__ __launch_bounds__(256) void k_attn(const ushort_t* __restrict__ qv_hi,
                                              const ushort_t* __restrict__ qv_lo,
                                              const int* __restrict__ st,
                                              float* __restrict__ lse_un,
                                              float* __restrict__ o_un, int bh0){
  __shared__ ushort_t tileh[128*72];
  __shared__ ushort_t tilel[128*72];
  __shared__ float nrm[128];
  __shared__ int spos[128];
  int blk = blockIdx.x;
  int hh = blk >> 9;
  int bh = bh0 + hh;
  int c = blk & (NCH_-1);
  int h = c >> 6;
  int b = bh >> 3, head = bh & 7;
  int cprev = (c + NCH_ - 1) & (NCH_-1);
  int tid = threadIdx.x;
  const int* stb = st + (size_t)bh * SORTN_;
  if (tid < 128){
    int gc = (tid < 64) ? c : cprev;
    spos[tid] = stb[gc*64 + (tid & 63)];
  }
  __syncthreads();
  // stage QK rows (split planes) + row norms (8-lane shuffle reduce, no atomics)
  for (int idx = tid; idx < 128*8; idx += 256){
    int j = idx >> 3, c8 = (idx & 7) * 8;
    size_t off = ((size_t)(b*T_ + spos[j]))*QV_N + head*DH_ + c8;
    uint4 hv = *(const uint4*)(qv_hi + off);
    uint4 lv = *(const uint4*)(qv_lo + off);
    *(uint4*)&tileh[j*72 + c8] = hv;
    *(uint4*)&tilel[j*72 + c8] = lv;
    const uint32 hw[4] = {hv.x,hv.y,hv.z,hv.w};
    const uint32 lw[4] = {lv.x,lv.y,lv.z,lv.w};
    float ss = 0.f;
    #pragma unroll
    for (int e=0;e<4;e++){
      float a0 = bf2f((ushort_t)(hw[e] & 0xffffu)) + bf2f((ushort_t)(lw[e] & 0xffffu));
      float a1 = bf2f((ushort_t)(hw[e] >> 16))     + bf2f((ushort_t)(lw[e] >> 16));
      ss += a0*a0 + a1*a1;
    }
    // the 8 lanes with the same j are consecutive: reduce across them
    ss += __shfl_xor(ss, 1);
    ss += __shfl_xor(ss, 2);
    ss += __shfl_xor(ss, 4);
    if ((tid & 7) == 0) nrm[j] = ss;
  }
  __syncthreads();
  if (tid < 128) nrm[tid] = 1.0f / sqrtf(fmaxf(nrm[tid], 1e-30f));
  int w = tid >> 6, lane = tid & 63;
  int lr = lane & 15, quad = lane >> 4;
  __syncthreads();
  // S = Qraw x Kraw^T
  v4f sacc[8];
  #pragma unroll
  for (int nt=0;nt<8;nt++) sacc[nt] = (v4f){0.f,0.f,0.f,0.f};
  #pragma unroll
  for (int ks=0; ks<2; ks++){
    int ao = (w*16 + lr)*72 + ks*32 + quad*8;
    v8s fah = *(const v8s*)&tileh[ao];
    v8s fal = *(const v8s*)&tilel[ao];
    #pragma unroll
    for (int nt=0; nt<8; nt++){
      int bo = (nt*16 + lr)*72 + ks*32 + quad*8;
      v8s fbh = *(const v8s*)&tileh[bo];
      v8s fbl = *(const v8s*)&tilel[bo];
      sacc[nt] = __builtin_amdgcn_mfma_f32_16x16x32_bf16(fah, fbh, sacc[nt],0,0,0);
      sacc[nt] = __builtin_amdgcn_mfma_f32_16x16x32_bf16(fah, fbl, sacc[nt],0,0,0);
      sacc[nt] = __builtin_amdgcn_mfma_f32_16x16x32_bf16(fal, fbh, sacc[nt],0,0,0);
    }
  }
  int q0 = w*16 + quad*4;
  int pq[4];
  #pragma unroll
  for (int r=0;r<4;r++) pq[r] = spos[q0 + r];
  float mrow[4] = {-3e38f,-3e38f,-3e38f,-3e38f};
  #pragma unroll
  for (int nt=0;nt<8;nt++){
    int j = nt*16 + lr;
    float sc = nrm[j] * 0.125f;
    int pk = spos[j];
    #pragma unroll
    for (int r=0;r<4;r++){
      float s = sacc[nt][r] * sc;
      if (pk == pq[r]) s = -5.0e4f;
      sacc[nt][r] = s;
      mrow[r] = fmaxf(mrow[r], s);
    }
  }
  #pragma unroll
  for (int r=0;r<4;r++){
    #pragma unroll
    for (int x=1;x<=8;x<<=1) mrow[r] = fmaxf(mrow[r], __shfl_xor(mrow[r], x));
  }
  float srow[4] = {0.f,0.f,0.f,0.f};
  #pragma unroll
  for (int nt=0;nt<8;nt++){
    #pragma unroll
    for (int r=0;r<4;r++){
      float e = __expf(sacc[nt][r] - mrow[r]);
      sacc[nt][r] = e;
      srow[r] += e;
    }
  }
  #pragma unroll
  for (int r=0;r<4;r++){
    #pragma unroll
    for (int x=1;x<=8;x<<=1) srow[r] += __shfl_xor(srow[r], x);
  }
  size_t obase = ((size_t)(hh*NHASH_ + h))*T_;
  if (lr == 0){
    #pragma unroll
    for (int r=0;r<4;r++)
      lse_un[obase + pq[r]] = mrow[r] + __logf(srow[r]);
  }
  float rs[4];
  #pragma unroll
  for (int r=0;r<4;r++) rs[r] = 1.0f / srow[r];
  __syncthreads();
  // P round-trip (rows 0..63, stride 136; <=2-way bank aliasing, free)
  #pragma unroll
  for (int nt=0;nt<8;nt++){
    #pragma unroll
    for (int r=0;r<4;r++){
      float p = sacc[nt][r] * rs[r];
      ushort_t ph, pl; split2(p, ph, pl);
      int o = (q0 + r)*136 + nt*16 + lr;
      tileh[o] = ph; tilel[o] = pl;
    }
  }
  __syncthreads();
  v8s pah[4], pal[4];
  #pragma unroll
  for (int ks=0; ks<4; ks++){
    int ao = (w*16 + lr)*136 + ks*32 + quad*8;
    pah[ks] = *(const v8s*)&tileh[ao];
    pal[ks] = *(const v8s*)&tilel[ao];
  }
  __syncthreads();
  // stage V transposed (swizzled columns: phys col = j ^ (d&56), d&56 == c8)
  for (int idx = tid; idx < 128*8; idx += 256){
    int j = idx >> 3, c8 = (idx & 7) * 8;
    size_t off = ((size_t)(b*T_ + spos[j]))*QV_N + 512 + head*DH_ + c8;
    uint4 hv = *(const uint4*)(qv_hi + off);
    uint4 lv = *(const uint4*)(qv_lo + off);
    const uint32 hw[4] = {hv.x,hv.y,hv.z,hv.w};
    const uint32 lw[4] = {lv.x,lv.y,lv.z,lv.w};
    int jp = j ^ c8;
    #pragma unroll
    for (int e=0;e<4;e++){
      tileh[(c8+2*e+0)*136 + jp] = (ushort_t)(hw[e] & 0xffffu);
      tileh[(c8+2*e+1)*136 + jp] = (ushort_t)(hw[e] >> 16);
      tilel[(c8+2*e+0)*136 + jp] = (ushort_t)(lw[e] & 0xffffu);
      tilel[(c8+2*e+1)*136 + jp] = (ushort_t)(lw[e] >> 16);
    }
  }
  __syncthreads();
  // O = P x V  (V reads un-swizzle: col ^ (row&56); stays 16B-aligned)
  v4f oacc[4];
  #pragma unroll
  for (int nt=0;nt<4;nt++) oacc[nt] = (v4f){0.f,0.f,0.f,0.f};
  #pragma unroll
  for (int ks=0; ks<4; ks++){
    #pragma unroll
    for (int nt=0; nt<4; nt++){
      int row = nt*16 + lr;
      int bo = row*136 + ((ks*32 + quad*8) ^ (row & 56));
      v8s vbh = *(const v8s*)&tileh[bo];
      v8s vbl = *(const v8s*)&tilel[bo];
      oacc[nt] = __builtin_amdgcn_mfma_f32_16x16x32_bf16(pah[ks], vbh, oacc[nt],0,0,0);
      oacc[nt] = __builtin_amdgcn_mfma_f32_16x16x32_bf16(pah[ks], vbl, oacc[nt],0,0,0);
      oacc[nt] = __builtin_amdgcn_mfma_f32_16x16x32_bf16(pal[ks], vbh, oacc[nt],0,0,0);
    }
  }
  #pragma unroll
  for (int r=0;r<4;r++){
    size_t rowoff = (obase + pq[r])*64;
    #pragma unroll
    for (int nt=0;nt<4;nt++){
      o_un[rowoff + nt*16 + lr] = oacc[nt][r];
    }
  }
}

// ---------------- combine hash rounds (coalesced)
__global__ __launch_bounds__(512) void k_combine(const float* __restrict__ lse_un,
                                                 const float* __restrict__ o_un,
                                                 ushort_t* __restrict__ ctx_hi,
                                                 ushort_t* __restrict__ ctx_lo,
                                                 int row0){
  int row = row0 + blockIdx.x;
  int t = row & (T_-1);
  int head = threadIdx.x >> 6, d = threadIdx.x & 63;
  float l[NHASH_];
  float m = -3.0e38f;
  #pragma unroll
  for (int h=0; h<NHASH_; h++){
    l[h] = lse_un[((size_t)(head*NHASH_ + h))*T_ + t];
    m = fmaxf(m, l[h]);
  }
  float sum = 0.f;
  #pragma unroll
  for (int h=0; h<NHASH_; h++){ l[h] = __expf(l[h]-m); sum += l[h]; }
  float rsv = 1.0f/sum;
  float acc = 0.f;
  #pragma unroll
  for (int h=0; h<NHASH_; h++){
    acc += l[h] * o_un[(((size_t)(head*NHASH_ + h))*T_ + t)*64 + d];
  }
  float o = acc * rsv;
  ushort_t hi, lo; split2(o, hi, lo);
  size_t off = (size_t)row*DIM_ + head*DH_ + d;
  ctx_hi[off] = hi; ctx_lo[off] = lo;
}

// ---------------- final head
__global__ __launch_bounds__(64) void k_final(const float* __restrict__ xn,
                                              const float* __restrict__ Wout,
                                              const float* __restrict__ bout,
                                              float* __restrict__ out){
  int row = blockIdx.x;
  int lane = threadIdx.x;
  const float* xr = xn + (size_t)row*DIM_;
  float p[TAGS_];
  #pragma unroll
  for (int n=0;n<TAGS_;n++) p[n] = 0.f;
  for (int d = lane; d < DIM_; d += 64){
    float x = xr[d];
    const float* wr = Wout + (size_t)d*TAGS_;
    #pragma unroll
    for (int n=0;n<TAGS_;n++) p[n] += x * wr[n];
  }
  #pragma unroll
  for (int n=0;n<TAGS_;n++){
    #pragma unroll
    for (int o=32;o>0;o>>=1) p[n] += __shfl_xor(p[n], o);
  }
  if (lane == 0){
    for (int n=0;n<TAGS_;n++) out[(size_t)row*TAGS_ + n] = p[n] + bout[n];
  }
}

extern "C" void kernel_launch(void* const* d_in, const int* in_sizes, int n_in,
                              void* d_out, int out_size, void* d_ws, size_t ws_size,
                              hipStream_t stream){
  const int* X         = (const int*)d_in[0];
  const float* tok     = (const float*)d_in[1];
  const float* ax1     = (const float*)d_in[2];
  const float* ax2     = (const float*)d_in[3];
  const float* Wqk     = (const float*)d_in[4];
  const float* Wv      = (const float*)d_in[5];
  const float* Wo      = (const float*)d_in[6];
  const float* ln1g    = (const float*)d_in[7];
  const float* ln1b    = (const float*)d_in[8];
  const float* W1      = (const float*)d_in[9];
  const float* b1      = (const float*)d_in[10];
  const float* W2      = (const float*)d_in[11];
  const float* b2      = (const float*)d_in[12];
  const float* ln2g    = (const float*)d_in[13];
  const float* ln2b    = (const float*)d_in[14];
  const float* lnfg    = (const float*)d_in[15];
  const float* lnfb    = (const float*)d_in[16];
  const float* WoutP   = (const float*)d_in[17];
  const float* boutP   = (const float*)d_in[18];
  const float* rot     = (const float*)d_in[19];
  float* out = (float*)d_out;

  size_t NX = (size_t)ROWS_*DIM_;            // 4,194,304
  size_t NS = (size_t)BH_*SORTN_;            // 524,288
  const size_t S3  = (size_t)DIM_*DIM_;      // 262,144
  const size_t SW1 = (size_t)DIM_*FF_;       // 1,048,576
  // per-layer weight arena (ushorts): qvw pair (2*2*S3) + wo pair + w1 pair + w2 pair
  const size_t WL  = 4*S3 + 2*S3 + 2*SW1 + 2*SW1;   // 5,767,168

  float* x1 = (float*)d_ws;
  float* x2 = x1 + NX;
  float* lse_un = x2 + NX;                   // NS floats
  int* buckets = (int*)(lse_un + NS);
  int* st  = buckets + NS;
  ushort_t* act_hi = (ushort_t*)(st + NS);   // [ROWS][512] split ctx/ln planes
  ushort_t* act_lo = act_hi + NX;
  ushort_t* qv_hi = act_lo + NX;             // [ROWS][1024] fused qk|v split planes
  ushort_t* qv_lo = qv_hi + (size_t)ROWS_*QV_N;
  ushort_t* warena = qv_lo + (size_t)ROWS_*QV_N;
  float* o_un = (float*)(warena + 2*WL);     // 64 MiB
  ushort_t* ffh_hi = (ushort_t*)o_un;        // FF hidden planes alias o_un
  ushort_t* ffh_lo = ffh_hi + (size_t)ROWS_*FF_;
  float* fbuf = (float*)o_un;                // final-LN fp32 (after FF dead)

  for (int l=0; l<2; l++){
    ushort_t* wl = warena + (size_t)l*WL;
    ushort_t* qvw_h = wl;                    // [1024][512]: rows 0-511 Wqk^T, 512-1023 Wv^T
    ushort_t* qvw_l = qvw_h + 2*S3;
    ushort_t* wo_h  = qvw_l + 2*S3;  ushort_t* wo_l = wo_h + S3;
    ushort_t* w1_h  = wo_l + S3;     ushort_t* w1_l = w1_h + SW1;
    ushort_t* w2_h  = w1_l + SW1;    ushort_t* w2_l = w2_h + SW1;
    k_splitw<<<dim3(DIM_/32, DIM_/32), 256, 0, stream>>>(Wqk + (size_t)l*S3, qvw_h, qvw_l, DIM_, DIM_);
    k_splitw<<<dim3(DIM_/32, DIM_/32), 256, 0, stream>>>(Wv  + (size_t)l*S3, qvw_h + S3, qvw_l + S3, DIM_, DIM_);
    k_splitw<<<dim3(DIM_/32, DIM_/32), 256, 0, stream>>>(Wo  + (size_t)l*S3, wo_h, wo_l, DIM_, DIM_);
    k_splitw<<<dim3(FF_/32,  DIM_/32), 256, 0, stream>>>(W1  + (size_t)l*SW1, w1_h, w1_l, DIM_, FF_);
    k_splitw<<<dim3(DIM_/32, FF_/32),  256, 0, stream>>>(W2  + (size_t)l*SW1, w2_h, w2_l, FF_, DIM_);
  }

  k_embed<<<ROWS_, 256, 0, stream>>>(X, tok, ax1, ax2, x1, x2);
  for (int l=0; l<2; l++){
    ushort_t* wl = warena + (size_t)l*WL;
    ushort_t* qvw_h = wl;
    ushort_t* qvw_l = qvw_h + 2*S3;
    ushort_t* wo_h  = qvw_l + 2*S3;  ushort_t* wo_l = wo_h + S3;
    ushort_t* w1_h  = wo_l + S3;     ushort_t* w1_l = w1_h + SW1;
    ushort_t* w2_h  = w1_l + SW1;    ushort_t* w2_l = w2_h + SW1;
    const float* rot_l = rot + (size_t)l*DH_*NHASH_*32;

    k_ln<<<ROWS_, 256, 0, stream>>>(x2, nullptr, ln1g + l*DIM_, ln1b + l*DIM_, nullptr, act_hi, act_lo);
    // qv: grid 512 (2/CU) — 2-deep counted-vmcnt pipeline + XCD swizzle
    k_gemm_mfma<2><<<dim3(QV_N/128, ROWS_/128), 256, 0, stream>>>(
        act_hi, act_lo, qvw_h, qvw_l, nullptr, nullptr, qv_hi, qv_lo, ROWS_, QV_N, DIM_, 4);
    k_buckets<<<dim3(T_/64, NHASH_, BH_), 256, 0, stream>>>(qv_hi, qv_lo, rot_l, buckets);
    k_sort<<<BH_*NHASH_, 256, 0, stream>>>(buckets, st);
    k_attn<<<8*NCH_, 256, 0, stream>>>(qv_hi, qv_lo, st, lse_un, o_un, 0);
    k_combine<<<T_, 512, 0, stream>>>(lse_un, o_un, act_hi, act_lo, 0);
    k_attn<<<8*NCH_, 256, 0, stream>>>(qv_hi, qv_lo, st, lse_un, o_un, 8);
    k_combine<<<T_, 512, 0, stream>>>(lse_un, o_un, act_hi, act_lo, T_);
    // wo: grid 256 (1/CU) — 2-deep pipeline + XCD swizzle
    k_gemm_mfma<2><<<dim3(DIM_/128, ROWS_/128), 256, 0, stream>>>(
        act_hi, act_lo, wo_h, wo_l, nullptr, x1, nullptr, nullptr, ROWS_, DIM_, DIM_, 1);
    k_ln<<<ROWS_, 256, 0, stream>>>(x1, nullptr, ln2g + l*DIM_, ln2b + l*DIM_, nullptr, act_hi, act_lo);
    // ff1: grid 1024 (4/CU) — single-buffer + XCD swizzle
    k_gemm_mfma<1><<<dim3(FF_/128, ROWS_/128), 256, 0, stream>>>(
        act_hi, act_lo, w1_h, w1_l, b1 + l*FF_, nullptr, ffh_hi, ffh_lo, ROWS_, FF_, DIM_, 2|4);
    // ff2: grid 256 (1/CU) — 2-deep pipeline + XCD swizzle
    k_gemm_mfma<2><<<dim3(DIM_/128, ROWS_/128), 256, 0, stream>>>(
        ffh_hi, ffh_lo, w2_h, w2_l, b2 + l*DIM_, x2, nullptr, nullptr, ROWS_, DIM_, FF_, 1);
  }
  k_ln<<<ROWS_, 256, 0, stream>>>(x1, x2, lnfg, lnfb, fbuf, nullptr, nullptr);
  k_final<<<ROWS_, 64, 0, stream>>>(fbuf, WoutP, boutP, out);
}

// Round 5
// 1303.893 us; speedup vs baseline: 1.0175x; 1.0175x over previous
//
#include <hip/hip_runtime.h>
#include <math.h>

typedef unsigned short ushort_t;
typedef unsigned int uint32;
typedef __attribute__((ext_vector_type(8))) short v8s;
typedef __attribute__((ext_vector_type(4))) float v4f;

#define B_ 2
#define T_ 4096
#define DIM_ 512
#define H_ 8
#define DH_ 64
#define BH_ 16
#define NHASH_ 8
#define NB_ 64
#define NCH_ 512
#define FF_ 2048
#define TAGS_ 17
#define ROWS_ 8192
#define SORTN_ 32768
#define QV_N 1024

__device__ __forceinline__ float bf2f(ushort_t u){
  return __uint_as_float(((uint32)u) << 16);
}
__device__ __forceinline__ ushort_t f2bf(float f){
  uint32 u = __float_as_uint(f);
  u += 0x7fffu + ((u >> 16) & 1u);
  return (ushort_t)(u >> 16);
}
__device__ __forceinline__ void split2(float a, ushort_t& h, ushort_t& l){
  h = f2bf(a);
  l = f2bf(a - bf2f(h));
}
// async global->LDS, 16B per lane; LDS dest = base + lane*16 (wave-uniform base)
__device__ __forceinline__ void gl16(const ushort_t* g, ushort_t* l){
  __builtin_amdgcn_global_load_lds(
      (const __attribute__((address_space(1))) unsigned int*)g,
      (__attribute__((address_space(3))) unsigned int*)l, 16, 0, 0);
}

// ---------------- embed
__global__ __launch_bounds__(256) void k_embed(const int* __restrict__ X,
                                               const float* __restrict__ tok,
                                               const float* __restrict__ ax1,
                                               const float* __restrict__ ax2,
                                               float* __restrict__ x1, float* __restrict__ x2){
  int row = blockIdx.x;
  int t = row & (T_-1);
  int tokid = X[row];
  size_t base = (size_t)row * DIM_;
  for (int d = threadIdx.x; d < DIM_; d += 256){
    float e = tok[(size_t)tokid*DIM_ + d];
    float p = (d < 256) ? ax1[(t>>6)*256 + d] : ax2[(t&63)*256 + (d-256)];
    float v = e + p;
    x1[base+d] = v; x2[base+d] = v;
  }
}

// ---------------- layernorm; writes fp32 (Yf) or split planes (Yh/Yl)
__global__ __launch_bounds__(256) void k_ln(const float* __restrict__ A, const float* __restrict__ Bb,
                                            const float* __restrict__ g, const float* __restrict__ be,
                                            float* __restrict__ Yf,
                                            ushort_t* __restrict__ Yh, ushort_t* __restrict__ Yl){
  int row = blockIdx.x; int tid = threadIdx.x;
  size_t base = (size_t)row * DIM_;
  float x0 = A[base+tid], x1v = A[base+tid+256];
  if (Bb){ x0 = 0.5f*(x0 + Bb[base+tid]); x1v = 0.5f*(x1v + Bb[base+tid+256]); }
  float s = x0 + x1v, sq = x0*x0 + x1v*x1v;
  for (int o=32;o>0;o>>=1){ s += __shfl_down(s,o); sq += __shfl_down(sq,o); }
  __shared__ float ls[4], lq[4], mm[2];
  if ((tid&63)==0){ ls[tid>>6]=s; lq[tid>>6]=sq; }
  __syncthreads();
  if (tid==0){
    float S=ls[0]+ls[1]+ls[2]+ls[3], Q=lq[0]+lq[1]+lq[2]+lq[3];
    float m = S*(1.0f/DIM_); float var = Q*(1.0f/DIM_) - m*m;
    mm[0]=m; mm[1]=1.0f/sqrtf(var+1e-5f);
  }
  __syncthreads();
  float m=mm[0], r=mm[1];
  float y0 = (x0 -m)*r*g[tid]     + be[tid];
  float y1 = (x1v-m)*r*g[tid+256] + be[tid+256];
  if (Yf){
    Yf[base+tid] = y0; Yf[base+tid+256] = y1;
  } else {
    ushort_t h, l;
    split2(y0, h, l); Yh[base+tid] = h;     Yl[base+tid] = l;
    split2(y1, h, l); Yh[base+tid+256] = h; Yl[base+tid+256] = l;
  }
}

// ---------------- weight pre-split + transpose
__global__ __launch_bounds__(256) void k_splitw(const float* __restrict__ W,
                                                ushort_t* __restrict__ Whi, ushort_t* __restrict__ Wlo,
                                                int K, int N){
  __shared__ float tile[32][33];
  int n0 = blockIdx.x*32, k0 = blockIdx.y*32;
  int tid = threadIdx.x;
  for (int idx=tid; idx<1024; idx+=256){
    int kk = idx>>5, nn = idx&31;
    tile[kk][nn] = W[(size_t)(k0+kk)*N + n0+nn];
  }
  __syncthreads();
  for (int idx=tid; idx<1024; idx+=256){
    int nn = idx>>5, kk = idx&31;
    float a = tile[kk][nn];
    ushort_t h, l; split2(a, h, l);
    size_t off = (size_t)(n0+nn)*K + k0+kk;
    Whi[off] = h; Wlo[off] = l;
  }
}

// ---------------- split-bf16 MFMA GEMM, 128x128 block, BK=32,
// global_load_lds staging, unpadded stride-32 LDS.
// XCD-aware block swizzle (T1, kept from R4: FETCH 143->57 MB on ff2).
// NBUF=1: m97 single-buffer (2 barriers/step) — for grids with >=4 blocks/CU.
// NBUF=2: simple 2-phase double-buffer (R3 structure, the verified winner):
//         issue next tile's global_load_lds BEFORE current tile's
//         ds_read+MFMA; ONE __syncthreads per step drains them after the
//         MFMA phase has hidden most of the (now L2-local) latency.
//         NOTE R4 lesson: counted-vmcnt/raw-barrier 2-deep REGRESSED here
//         (T4 requires the 8-phase interleave regime; m230/m233).
// flags: 1 = += into outF, 2 = gelu, 4 = split output planes
template<int NBUF>
__global__ __launch_bounds__(256) void k_gemm_mfma(
    const ushort_t* __restrict__ A_hi, const ushort_t* __restrict__ A_lo,
    const ushort_t* __restrict__ Bt_hi, const ushort_t* __restrict__ Bt_lo,
    const float* __restrict__ bias,
    float* __restrict__ outF,
    ushort_t* __restrict__ out_hi, ushort_t* __restrict__ out_lo,
    int M, int N, int K, int flags){
  // layout: [buf][plane][128*32]
  __shared__ ushort_t As[NBUF*2*128*32];
  __shared__ ushort_t Bs[NBUF*2*128*32];
  int tid = threadIdx.x;
  // XCD-aware swizzle (bijective when gridDim.y % 8 == 0)
  int nx = gridDim.x, ny = gridDim.y;
  int bn_i, bm_i;
  if ((ny & 7) == 0){
    int flat = blockIdx.x + nx*blockIdx.y;
    int xcd = flat & 7, j = flat >> 3;
    bn_i = j % nx;
    bm_i = xcd*(ny>>3) + j/nx;
  } else {
    bn_i = blockIdx.x; bm_i = blockIdx.y;
  }
  int bn = bn_i * 128, bm = bm_i * 128;
  int w = tid>>6, lane = tid&63;
  int wm = w>>1, wn = w&1;
  int lr = lane&15, quad = lane>>4;
  int lrow = lane>>2, lcol = (lane&3)*8;
  v4f acc[4][4];
  #pragma unroll
  for (int mt=0;mt<4;mt++)
    #pragma unroll
    for (int nt=0;nt<4;nt++) acc[mt][nt] = (v4f){0.f,0.f,0.f,0.f};

  v8s fa_h[4], fa_l[4], fb_h[4], fb_l[4];

  auto STAGE = [&](int buf, int k0){
    #pragma unroll
    for (int i=0;i<2;i++){
      int cr = i*64 + w*16 + lrow;               // tile row this lane stages
      int lb = buf*8192 + (i*64 + w*16)*32;      // wave-uniform LDS base (ushorts)
      size_t goA = (size_t)(bm+cr)*K + k0 + lcol;
      size_t goB = (size_t)(bn+cr)*K + k0 + lcol;
      gl16(A_hi + goA, &As[lb]);
      gl16(A_lo + goA, &As[lb + 4096]);
      gl16(Bt_hi + goB, &Bs[lb]);
      gl16(Bt_lo + goB, &Bs[lb + 4096]);
    }
  };
  auto LOADFRAGS = [&](int buf){
    int bo = buf*8192;
    #pragma unroll
    for (int mt=0;mt<4;mt++){
      int ro = (wm*64 + mt*16 + lr)*32 + quad*8;
      fa_h[mt] = *(const v8s*)&As[bo + ro];
      fa_l[mt] = *(const v8s*)&As[bo + 4096 + ro];
    }
    #pragma unroll
    for (int nt=0;nt<4;nt++){
      int ro = (wn*64 + nt*16 + lr)*32 + quad*8;
      fb_h[nt] = *(const v8s*)&Bs[bo + ro];
      fb_l[nt] = *(const v8s*)&Bs[bo + 4096 + ro];
    }
  };
  auto DOMFMA = [&](){
    #pragma unroll
    for (int mt=0;mt<4;mt++)
      #pragma unroll
      for (int nt=0;nt<4;nt++){
        acc[mt][nt] = __builtin_amdgcn_mfma_f32_16x16x32_bf16(fa_h[mt], fb_h[nt], acc[mt][nt], 0,0,0);
        acc[mt][nt] = __builtin_amdgcn_mfma_f32_16x16x32_bf16(fa_h[mt], fb_l[nt], acc[mt][nt], 0,0,0);
        acc[mt][nt] = __builtin_amdgcn_mfma_f32_16x16x32_bf16(fa_l[mt], fb_h[nt], acc[mt][nt], 0,0,0);
      }
  };

  if constexpr (NBUF == 2){
    STAGE(0, 0);
    __syncthreads();                // drain prologue loads
    int cur = 0;
    for (int k0=0; k0<K; k0+=32){
      if (k0+32 < K) STAGE(cur^1, k0+32);   // next tile in flight during MFMA
      LOADFRAGS(cur);
      DOMFMA();
      __syncthreads();              // single barrier per step: drains next-tile loads
      cur ^= 1;
    }
  } else {
    for (int k0=0; k0<K; k0+=32){
      STAGE(0, k0);
      __syncthreads();
      LOADFRAGS(0);
      DOMFMA();
      __syncthreads();
    }
  }

  #pragma unroll
  for (int mt=0;mt<4;mt++){
    #pragma unroll
    for (int nt=0;nt<4;nt++){
      int col = bn + wn*64 + nt*16 + lr;
      float bv = bias ? bias[col] : 0.f;
      #pragma unroll
      for (int r=0;r<4;r++){
        int row = bm + wm*64 + mt*16 + quad*4 + r;
        float v = acc[mt][nt][r] + bv;
        if (flags & 2){
          float x = v;
          float inner = 0.7978845608028654f * (x + 0.044715f*x*x*x);
          // tanh(i) = 1 - 2/(exp(2i)+1), fast-exp form
          float t = 1.0f - 2.0f / (__expf(2.0f*inner) + 1.0f);
          v = 0.5f*x*(1.0f + t);
        }
        size_t off = (size_t)row*N + col;
        if (flags & 4){
          ushort_t h, l; split2(v, h, l);
          out_hi[off] = h; out_lo[off] = l;
        } else if (flags & 1){
          outF[off] += v;
        } else {
          outF[off] = v;
        }
      }
    }
  }
}

// ---------------- LSH bucketing from split qv planes
__global__ __launch_bounds__(256) void k_buckets(const ushort_t* __restrict__ qv_hi,
                                                 const ushort_t* __restrict__ qv_lo,
                                                 const float* __restrict__ rot,
                                                 int* __restrict__ buckets){
  __shared__ float rotS[DH_][32];
  __shared__ float qs[64][68];
  int t0 = blockIdx.x * 64;
  int h  = blockIdx.y;
  int bh = blockIdx.z;
  int b = bh >> 3, head = bh & 7;
  int tid = threadIdx.x;
  for (int idx = tid; idx < DH_*32; idx += 256){
    int d = idx >> 5, j = idx & 31;
    rotS[d][j] = rot[(size_t)d*(NHASH_*32) + h*32 + j];
  }
  for (int idx = tid; idx < 64*DH_; idx += 256){
    int tt = idx >> 6, d = idx & 63;
    size_t off = ((size_t)(b*T_ + t0 + tt))*QV_N + head*DH_ + d;
    qs[tt][d] = bf2f(qv_hi[off]) + bf2f(qv_lo[off]);
  }
  __syncthreads();
  int tt = tid >> 2, lane = tid & 3;
  int j0 = lane * 8;
  float r8[8];
  #pragma unroll
  for (int k=0;k<8;k++) r8[k] = 0.f;
  for (int d=0; d<DH_; d++){
    float q = qs[tt][d];
    #pragma unroll
    for (int k=0;k<8;k++) r8[k] += q * rotS[d][j0+k];
  }
  float best = r8[0]; int bidx = j0;
  #pragma unroll
  for (int k=1;k<8;k++){ if (r8[k] > best){ best = r8[k]; bidx = j0+k; } }
  #pragma unroll
  for (int k=0;k<8;k++){ float v = -r8[k]; if (v > best){ best = v; bidx = 32+j0+k; } }
  #pragma unroll
  for (int x=1; x<=2; x<<=1){
    float ov = __shfl_xor(best, x);
    int   oi = __shfl_xor(bidx, x);
    if (ov > best || (ov == best && oi < bidx)){ best = ov; bidx = oi; }
  }
  if (lane == 0)
    buckets[((size_t)bh*NHASH_ + h)*T_ + t0 + tt] = bidx;
}

// ---------------- stable counting sort per (bh, hash)
__global__ __launch_bounds__(256) void k_sort(const int* __restrict__ buckets,
                                              int* __restrict__ st){
  int blk = blockIdx.x;
  int bh = blk >> 3, h = blk & 7;
  const int* bptr = buckets + ((size_t)bh*NHASH_ + h)*T_;
  __shared__ unsigned char bb[T_];
  __shared__ int cnt[4][NB_];
  __shared__ int offs[NB_];
  int tid = threadIdx.x;
  for (int i = tid; i < T_; i += 256) bb[i] = (unsigned char)bptr[i];
  __syncthreads();
  int q = tid >> 6, j = tid & 63;
  int c0 = 0;
  for (int t = q*1024; t < q*1024 + 1024; t++) c0 += (bb[t]==j) ? 1 : 0;
  cnt[q][j] = c0;
  __syncthreads();
  if (tid == 0){
    int run = 0;
    for (int jj=0; jj<NB_; jj++){
      offs[jj] = run;
      run += cnt[0][jj] + cnt[1][jj] + cnt[2][jj] + cnt[3][jj];
    }
  }
  __syncthreads();
  int off = offs[j];
  for (int qq=0; qq<q; qq++) off += cnt[qq][j];
  size_t base = (size_t)bh*SORTN_ + (size_t)h*T_;
  for (int t = q*1024; t < q*1024 + 1024; t++){
    if (bb[t]==j){ st[base+off] = t; off++; }
  }
}

// ---------------- flash-MFMA LSH attention; inputs pre-split qv planes
// V^T LDS region is XOR-swizzled: element (d, j) lives at d*136 + (j ^ (d&56)).
__global__ __launch_bounds__(256) void k_attn(const ushort_t* __restrict__ qv_hi,
                                              const ushort_t* __restrict__ qv_lo,
                                              const int* __restrict__ st,
                                              float* __restrict__ lse_un,
                                              float* __restrict__ o_un, int bh0){
  __shared__ ushort_t tileh[128*72];
  __shared__ ushort_t tilel[128*72];
  __shared__ float nrm[128];
  __shared__ int spos[128];
  int blk = blockIdx.x;
  int hh = blk >> 9;
  int bh = bh0 + hh;
  int c = blk & (NCH_-1);
  int h = c >> 6;
  int b = bh >> 3, head = bh & 7;
  int cprev = (c + NCH_ - 1) & (NCH_-1);
  int tid = threadIdx.x;
  const int* stb = st + (size_t)bh * SORTN_;
  if (tid < 128){
    int gc = (tid < 64) ? c : cprev;
    spos[tid] = stb[gc*64 + (tid & 63)];
  }
  __syncthreads();
  // stage QK rows (split planes) + row norms (8-lane shuffle reduce, no atomics)
  for (int idx = tid; idx < 128*8; idx += 256){
    int j = idx >> 3, c8 = (idx & 7) * 8;
    size_t off = ((size_t)(b*T_ + spos[j]))*QV_N + head*DH_ + c8;
    uint4 hv = *(const uint4*)(qv_hi + off);
    uint4 lv = *(const uint4*)(qv_lo + off);
    *(uint4*)&tileh[j*72 + c8] = hv;
    *(uint4*)&tilel[j*72 + c8] = lv;
    const uint32 hw[4] = {hv.x,hv.y,hv.z,hv.w};
    const uint32 lw[4] = {lv.x,lv.y,lv.z,lv.w};
    float ss = 0.f;
    #pragma unroll
    for (int e=0;e<4;e++){
      float a0 = bf2f((ushort_t)(hw[e] & 0xffffu)) + bf2f((ushort_t)(lw[e] & 0xffffu));
      float a1 = bf2f((ushort_t)(hw[e] >> 16))     + bf2f((ushort_t)(lw[e] >> 16));
      ss += a0*a0 + a1*a1;
    }
    // the 8 lanes with the same j are consecutive: reduce across them
    ss += __shfl_xor(ss, 1);
    ss += __shfl_xor(ss, 2);
    ss += __shfl_xor(ss, 4);
    if ((tid & 7) == 0) nrm[j] = ss;
  }
  __syncthreads();
  if (tid < 128) nrm[tid] = 1.0f / sqrtf(fmaxf(nrm[tid], 1e-30f));
  int w = tid >> 6, lane = tid & 63;
  int lr = lane & 15, quad = lane >> 4;
  __syncthreads();
  // S = Qraw x Kraw^T
  v4f sacc[8];
  #pragma unroll
  for (int nt=0;nt<8;nt++) sacc[nt] = (v4f){0.f,0.f,0.f,0.f};
  #pragma unroll
  for (int ks=0; ks<2; ks++){
    int ao = (w*16 + lr)*72 + ks*32 + quad*8;
    v8s fah = *(const v8s*)&tileh[ao];
    v8s fal = *(const v8s*)&tilel[ao];
    #pragma unroll
    for (int nt=0; nt<8; nt++){
      int bo = (nt*16 + lr)*72 + ks*32 + quad*8;
      v8s fbh = *(const v8s*)&tileh[bo];
      v8s fbl = *(const v8s*)&tilel[bo];
      sacc[nt] = __builtin_amdgcn_mfma_f32_16x16x32_bf16(fah, fbh, sacc[nt],0,0,0);
      sacc[nt] = __builtin_amdgcn_mfma_f32_16x16x32_bf16(fah, fbl, sacc[nt],0,0,0);
      sacc[nt] = __builtin_amdgcn_mfma_f32_16x16x32_bf16(fal, fbh, sacc[nt],0,0,0);
    }
  }
  int q0 = w*16 + quad*4;
  int pq[4];
  #pragma unroll
  for (int r=0;r<4;r++) pq[r] = spos[q0 + r];
  float mrow[4] = {-3e38f,-3e38f,-3e38f,-3e38f};
  #pragma unroll
  for (int nt=0;nt<8;nt++){
    int j = nt*16 + lr;
    float sc = nrm[j] * 0.125f;
    int pk = spos[j];
    #pragma unroll
    for (int r=0;r<4;r++){
      float s = sacc[nt][r] * sc;
      if (pk == pq[r]) s = -5.0e4f;
      sacc[nt][r] = s;
      mrow[r] = fmaxf(mrow[r], s);
    }
  }
  #pragma unroll
  for (int r=0;r<4;r++){
    #pragma unroll
    for (int x=1;x<=8;x<<=1) mrow[r] = fmaxf(mrow[r], __shfl_xor(mrow[r], x));
  }
  float srow[4] = {0.f,0.f,0.f,0.f};
  #pragma unroll
  for (int nt=0;nt<8;nt++){
    #pragma unroll
    for (int r=0;r<4;r++){
      float e = __expf(sacc[nt][r] - mrow[r]);
      sacc[nt][r] = e;
      srow[r] += e;
    }
  }
  #pragma unroll
  for (int r=0;r<4;r++){
    #pragma unroll
    for (int x=1;x<=8;x<<=1) srow[r] += __shfl_xor(srow[r], x);
  }
  size_t obase = ((size_t)(hh*NHASH_ + h))*T_;
  if (lr == 0){
    #pragma unroll
    for (int r=0;r<4;r++)
      lse_un[obase + pq[r]] = mrow[r] + __logf(srow[r]);
  }
  float rs[4];
  #pragma unroll
  for (int r=0;r<4;r++) rs[r] = 1.0f / srow[r];
  __syncthreads();
  // P round-trip (rows 0..63, stride 136; <=2-way bank aliasing, free)
  #pragma unroll
  for (int nt=0;nt<8;nt++){
    #pragma unroll
    for (int r=0;r<4;r++){
      float p = sacc[nt][r] * rs[r];
      ushort_t ph, pl; split2(p, ph, pl);
      int o = (q0 + r)*136 + nt*16 + lr;
      tileh[o] = ph; tilel[o] = pl;
    }
  }
  __syncthreads();
  v8s pah[4], pal[4];
  #pragma unroll
  for (int ks=0; ks<4; ks++){
    int ao = (w*16 + lr)*136 + ks*32 + quad*8;
    pah[ks] = *(const v8s*)&tileh[ao];
    pal[ks] = *(const v8s*)&tilel[ao];
  }
  __syncthreads();
  // stage V transposed (swizzled columns: phys col = j ^ (d&56), d&56 == c8)
  for (int idx = tid; idx < 128*8; idx += 256){
    int j = idx >> 3, c8 = (idx & 7) * 8;
    size_t off = ((size_t)(b*T_ + spos[j]))*QV_N + 512 + head*DH_ + c8;
    uint4 hv = *(const uint4*)(qv_hi + off);
    uint4 lv = *(const uint4*)(qv_lo + off);
    const uint32 hw[4] = {hv.x,hv.y,hv.z,hv.w};
    const uint32 lw[4] = {lv.x,lv.y,lv.z,lv.w};
    int jp = j ^ c8;
    #pragma unroll
    for (int e=0;e<4;e++){
      tileh[(c8+2*e+0)*136 + jp] = (ushort_t)(hw[e] & 0xffffu);
      tileh[(c8+2*e+1)*136 + jp] = (ushort_t)(hw[e] >> 16);
      tilel[(c8+2*e+0)*136 + jp] = (ushort_t)(lw[e] & 0xffffu);
      tilel[(c8+2*e+1)*136 + jp] = (ushort_t)(lw[e] >> 16);
    }
  }
  __syncthreads();
  // O = P x V  (V reads un-swizzle: col ^ (row&56); stays 16B-aligned)
  v4f oacc[4];
  #pragma unroll
  for (int nt=0;nt<4;nt++) oacc[nt] = (v4f){0.f,0.f,0.f,0.f};
  #pragma unroll
  for (int ks=0; ks<4; ks++){
    #pragma unroll
    for (int nt=0; nt<4; nt++){
      int row = nt*16 + lr;
      int bo = row*136 + ((ks*32 + quad*8) ^ (row & 56));
      v8s vbh = *(const v8s*)&tileh[bo];
      v8s vbl = *(const v8s*)&tilel[bo];
      oacc[nt] = __builtin_amdgcn_mfma_f32_16x16x32_bf16(pah[ks], vbh, oacc[nt],0,0,0);
      oacc[nt] = __builtin_amdgcn_mfma_f32_16x16x32_bf16(pah[ks], vbl, oacc[nt],0,0,0);
      oacc[nt] = __builtin_amdgcn_mfma_f32_16x16x32_bf16(pal[ks], vbh, oacc[nt],0,0,0);
    }
  }
  #pragma unroll
  for (int r=0;r<4;r++){
    size_t rowoff = (obase + pq[r])*64;
    #pragma unroll
    for (int nt=0;nt<4;nt++){
      o_un[rowoff + nt*16 + lr] = oacc[nt][r];
    }
  }
}

// ---------------- combine hash rounds (coalesced)
__global__ __launch_bounds__(512) void k_combine(const float* __restrict__ lse_un,
                                                 const float* __restrict__ o_un,
                                                 ushort_t* __restrict__ ctx_hi,
                                                 ushort_t* __restrict__ ctx_lo,
                                                 int row0){
  int row = row0 + blockIdx.x;
  int t = row & (T_-1);
  int head = threadIdx.x >> 6, d = threadIdx.x & 63;
  float l[NHASH_];
  float m = -3.0e38f;
  #pragma unroll
  for (int h=0; h<NHASH_; h++){
    l[h] = lse_un[((size_t)(head*NHASH_ + h))*T_ + t];
    m = fmaxf(m, l[h]);
  }
  float sum = 0.f;
  #pragma unroll
  for (int h=0; h<NHASH_; h++){ l[h] = __expf(l[h]-m); sum += l[h]; }
  float rsv = 1.0f/sum;
  float acc = 0.f;
  #pragma unroll
  for (int h=0; h<NHASH_; h++){
    acc += l[h] * o_un[(((size_t)(head*NHASH_ + h))*T_ + t)*64 + d];
  }
  float o = acc * rsv;
  ushort_t hi, lo; split2(o, hi, lo);
  size_t off = (size_t)row*DIM_ + head*DH_ + d;
  ctx_hi[off] = hi; ctx_lo[off] = lo;
}

// ---------------- final head
__global__ __launch_bounds__(64) void k_final(const float* __restrict__ xn,
                                              const float* __restrict__ Wout,
                                              const float* __restrict__ bout,
                                              float* __restrict__ out){
  int row = blockIdx.x;
  int lane = threadIdx.x;
  const float* xr = xn + (size_t)row*DIM_;
  float p[TAGS_];
  #pragma unroll
  for (int n=0;n<TAGS_;n++) p[n] = 0.f;
  for (int d = lane; d < DIM_; d += 64){
    float x = xr[d];
    const float* wr = Wout + (size_t)d*TAGS_;
    #pragma unroll
    for (int n=0;n<TAGS_;n++) p[n] += x * wr[n];
  }
  #pragma unroll
  for (int n=0;n<TAGS_;n++){
    #pragma unroll
    for (int o=32;o>0;o>>=1) p[n] += __shfl_xor(p[n], o);
  }
  if (lane == 0){
    for (int n=0;n<TAGS_;n++) out[(size_t)row*TAGS_ + n] = p[n] + bout[n];
  }
}

extern "C" void kernel_launch(void* const* d_in, const int* in_sizes, int n_in,
                              void* d_out, int out_size, void* d_ws, size_t ws_size,
                              hipStream_t stream){
  const int* X         = (const int*)d_in[0];
  const float* tok     = (const float*)d_in[1];
  const float* ax1     = (const float*)d_in[2];
  const float* ax2     = (const float*)d_in[3];
  const float* Wqk     = (const float*)d_in[4];
  const float* Wv      = (const float*)d_in[5];
  const float* Wo      = (const float*)d_in[6];
  const float* ln1g    = (const float*)d_in[7];
  const float* ln1b    = (const float*)d_in[8];
  const float* W1      = (const float*)d_in[9];
  const float* b1      = (const float*)d_in[10];
  const float* W2      = (const float*)d_in[11];
  const float* b2      = (const float*)d_in[12];
  const float* ln2g    = (const float*)d_in[13];
  const float* ln2b    = (const float*)d_in[14];
  const float* lnfg    = (const float*)d_in[15];
  const float* lnfb    = (const float*)d_in[16];
  const float* WoutP   = (const float*)d_in[17];
  const float* boutP   = (const float*)d_in[18];
  const float* rot     = (const float*)d_in[19];
  float* out = (float*)d_out;

  size_t NX = (size_t)ROWS_*DIM_;            // 4,194,304
  size_t NS = (size_t)BH_*SORTN_;            // 524,288
  const size_t S3  = (size_t)DIM_*DIM_;      // 262,144
  const size_t SW1 = (size_t)DIM_*FF_;       // 1,048,576
  // per-layer weight arena (ushorts): qvw pair (2*2*S3) + wo pair + w1 pair + w2 pair
  const size_t WL  = 4*S3 + 2*S3 + 2*SW1 + 2*SW1;   // 5,767,168

  float* x1 = (float*)d_ws;
  float* x2 = x1 + NX;
  float* lse_un = x2 + NX;                   // NS floats
  int* buckets = (int*)(lse_un + NS);
  int* st  = buckets + NS;
  ushort_t* act_hi = (ushort_t*)(st + NS);   // [ROWS][512] split ctx/ln planes
  ushort_t* act_lo = act_hi + NX;
  ushort_t* qv_hi = act_lo + NX;             // [ROWS][1024] fused qk|v split planes
  ushort_t* qv_lo = qv_hi + (size_t)ROWS_*QV_N;
  ushort_t* warena = qv_lo + (size_t)ROWS_*QV_N;
  float* o_un = (float*)(warena + 2*WL);     // 64 MiB
  ushort_t* ffh_hi = (ushort_t*)o_un;        // FF hidden planes alias o_un
  ushort_t* ffh_lo = ffh_hi + (size_t)ROWS_*FF_;
  float* fbuf = (float*)o_un;                // final-LN fp32 (after FF dead)

  for (int l=0; l<2; l++){
    ushort_t* wl = warena + (size_t)l*WL;
    ushort_t* qvw_h = wl;                    // [1024][512]: rows 0-511 Wqk^T, 512-1023 Wv^T
    ushort_t* qvw_l = qvw_h + 2*S3;
    ushort_t* wo_h  = qvw_l + 2*S3;  ushort_t* wo_l = wo_h + S3;
    ushort_t* w1_h  = wo_l + S3;     ushort_t* w1_l = w1_h + SW1;
    ushort_t* w2_h  = w1_l + SW1;    ushort_t* w2_l = w2_h + SW1;
    k_splitw<<<dim3(DIM_/32, DIM_/32), 256, 0, stream>>>(Wqk + (size_t)l*S3, qvw_h, qvw_l, DIM_, DIM_);
    k_splitw<<<dim3(DIM_/32, DIM_/32), 256, 0, stream>>>(Wv  + (size_t)l*S3, qvw_h + S3, qvw_l + S3, DIM_, DIM_);
    k_splitw<<<dim3(DIM_/32, DIM_/32), 256, 0, stream>>>(Wo  + (size_t)l*S3, wo_h, wo_l, DIM_, DIM_);
    k_splitw<<<dim3(FF_/32,  DIM_/32), 256, 0, stream>>>(W1  + (size_t)l*SW1, w1_h, w1_l, DIM_, FF_);
    k_splitw<<<dim3(DIM_/32, FF_/32),  256, 0, stream>>>(W2  + (size_t)l*SW1, w2_h, w2_l, FF_, DIM_);
  }

  k_embed<<<ROWS_, 256, 0, stream>>>(X, tok, ax1, ax2, x1, x2);
  for (int l=0; l<2; l++){
    ushort_t* wl = warena + (size_t)l*WL;
    ushort_t* qvw_h = wl;
    ushort_t* qvw_l = qvw_h + 2*S3;
    ushort_t* wo_h  = qvw_l + 2*S3;  ushort_t* wo_l = wo_h + S3;
    ushort_t* w1_h  = wo_l + S3;     ushort_t* w1_l = w1_h + SW1;
    ushort_t* w2_h  = w1_l + SW1;    ushort_t* w2_l = w2_h + SW1;
    const float* rot_l = rot + (size_t)l*DH_*NHASH_*32;

    k_ln<<<ROWS_, 256, 0, stream>>>(x2, nullptr, ln1g + l*DIM_, ln1b + l*DIM_, nullptr, act_hi, act_lo);
    // qv: grid 512 (2/CU) — 2-phase dbuf + XCD swizzle
    k_gemm_mfma<2><<<dim3(QV_N/128, ROWS_/128), 256, 0, stream>>>(
        act_hi, act_lo, qvw_h, qvw_l, nullptr, nullptr, qv_hi, qv_lo, ROWS_, QV_N, DIM_, 4);
    k_buckets<<<dim3(T_/64, NHASH_, BH_), 256, 0, stream>>>(qv_hi, qv_lo, rot_l, buckets);
    k_sort<<<BH_*NHASH_, 256, 0, stream>>>(buckets, st);
    k_attn<<<8*NCH_, 256, 0, stream>>>(qv_hi, qv_lo, st, lse_un, o_un, 0);
    k_combine<<<T_, 512, 0, stream>>>(lse_un, o_un, act_hi, act_lo, 0);
    k_attn<<<8*NCH_, 256, 0, stream>>>(qv_hi, qv_lo, st, lse_un, o_un, 8);
    k_combine<<<T_, 512, 0, stream>>>(lse_un, o_un, act_hi, act_lo, T_);
    // wo: grid 256 (1/CU) — 2-phase dbuf + XCD swizzle
    k_gemm_mfma<2><<<dim3(DIM_/128, ROWS_/128), 256, 0, stream>>>(
        act_hi, act_lo, wo_h, wo_l, nullptr, x1, nullptr, nullptr, ROWS_, DIM_, DIM_, 1);
    k_ln<<<ROWS_, 256, 0, stream>>>(x1, nullptr, ln2g + l*DIM_, ln2b + l*DIM_, nullptr, act_hi, act_lo);
    // ff1: grid 1024 (4/CU) — single-buffer + XCD swizzle
    k_gemm_mfma<1><<<dim3(FF_/128, ROWS_/128), 256, 0, stream>>>(
        act_hi, act_lo, w1_h, w1_l, b1 + l*FF_, nullptr, ffh_hi, ffh_lo, ROWS_, FF_, DIM_, 2|4);
    // ff2: grid 256 (1/CU) — 2-phase dbuf + XCD swizzle
    k_gemm_mfma<2><<<dim3(DIM_/128, ROWS_/128), 256, 0, stream>>>(
        ffh_hi, ffh_lo, w2_h, w2_l, b2 + l*DIM_, x2, nullptr, nullptr, ROWS_, DIM_, FF_, 1);
  }
  k_ln<<<ROWS_, 256, 0, stream>>>(x1, x2, lnfg, lnfb, fbuf, nullptr, nullptr);
  k_final<<<ROWS_, 64, 0, stream>>>(fbuf, WoutP, boutP, out);
}

// Round 6
// 1238.855 us; speedup vs baseline: 1.0709x; 1.0525x over previous
//
#include <hip/hip_runtime.h>
#include <math.h>

typedef unsigned short ushort_t;
typedef unsigned int uint32;
typedef __attribute__((ext_vector_type(8))) short v8s;
typedef __attribute__((ext_vector_type(4))) float v4f;

#define B_ 2
#define T_ 4096
#define DIM_ 512
#define H_ 8
#define DH_ 64
#define BH_ 16
#define NHASH_ 8
#define NB_ 64
#define NCH_ 512
#define FF_ 2048
#define TAGS_ 17
#define ROWS_ 8192
#define SORTN_ 32768
#define QV_N 1024

__device__ __forceinline__ float bf2f(ushort_t u){
  return __uint_as_float(((uint32)u) << 16);
}
__device__ __forceinline__ ushort_t f2bf(float f){
  uint32 u = __float_as_uint(f);
  u += 0x7fffu + ((u >> 16) & 1u);
  return (ushort_t)(u >> 16);
}
__device__ __forceinline__ void split2(float a, ushort_t& h, ushort_t& l){
  h = f2bf(a);
  l = f2bf(a - bf2f(h));
}
// async global->LDS, 16B per lane; LDS dest = base + lane*16 (wave-uniform base)
__device__ __forceinline__ void gl16(const ushort_t* g, ushort_t* l){
  __builtin_amdgcn_global_load_lds(
      (const __attribute__((address_space(1))) unsigned int*)g,
      (__attribute__((address_space(3))) unsigned int*)l, 16, 0, 0);
}

// ---------------- embed
__global__ __launch_bounds__(256) void k_embed(const int* __restrict__ X,
                                               const float* __restrict__ tok,
                                               const float* __restrict__ ax1,
                                               const float* __restrict__ ax2,
                                               float* __restrict__ x1, float* __restrict__ x2){
  int row = blockIdx.x;
  int t = row & (T_-1);
  int tokid = X[row];
  size_t base = (size_t)row * DIM_;
  for (int d = threadIdx.x; d < DIM_; d += 256){
    float e = tok[(size_t)tokid*DIM_ + d];
    float p = (d < 256) ? ax1[(t>>6)*256 + d] : ax2[(t&63)*256 + (d-256)];
    float v = e + p;
    x1[base+d] = v; x2[base+d] = v;
  }
}

// ---------------- layernorm; writes fp32 (Yf) or split planes (Yh/Yl)
__global__ __launch_bounds__(256) void k_ln(const float* __restrict__ A, const float* __restrict__ Bb,
                                            const float* __restrict__ g, const float* __restrict__ be,
                                            float* __restrict__ Yf,
                                            ushort_t* __restrict__ Yh, ushort_t* __restrict__ Yl){
  int row = blockIdx.x; int tid = threadIdx.x;
  size_t base = (size_t)row * DIM_;
  float x0 = A[base+tid], x1v = A[base+tid+256];
  if (Bb){ x0 = 0.5f*(x0 + Bb[base+tid]); x1v = 0.5f*(x1v + Bb[base+tid+256]); }
  float s = x0 + x1v, sq = x0*x0 + x1v*x1v;
  for (int o=32;o>0;o>>=1){ s += __shfl_down(s,o); sq += __shfl_down(sq,o); }
  __shared__ float ls[4], lq[4], mm[2];
  if ((tid&63)==0){ ls[tid>>6]=s; lq[tid>>6]=sq; }
  __syncthreads();
  if (tid==0){
    float S=ls[0]+ls[1]+ls[2]+ls[3], Q=lq[0]+lq[1]+lq[2]+lq[3];
    float m = S*(1.0f/DIM_); float var = Q*(1.0f/DIM_) - m*m;
    mm[0]=m; mm[1]=1.0f/sqrtf(var+1e-5f);
  }
  __syncthreads();
  float m=mm[0], r=mm[1];
  float y0 = (x0 -m)*r*g[tid]     + be[tid];
  float y1 = (x1v-m)*r*g[tid+256] + be[tid+256];
  if (Yf){
    Yf[base+tid] = y0; Yf[base+tid+256] = y1;
  } else {
    ushort_t h, l;
    split2(y0, h, l); Yh[base+tid] = h;     Yl[base+tid] = l;
    split2(y1, h, l); Yh[base+tid+256] = h; Yl[base+tid+256] = l;
  }
}

// ---------------- weight pre-split + transpose
__global__ __launch_bounds__(256) void k_splitw(const float* __restrict__ W,
                                                ushort_t* __restrict__ Whi, ushort_t* __restrict__ Wlo,
                                                int K, int N){
  __shared__ float tile[32][33];
  int n0 = blockIdx.x*32, k0 = blockIdx.y*32;
  int tid = threadIdx.x;
  for (int idx=tid; idx<1024; idx+=256){
    int kk = idx>>5, nn = idx&31;
    tile[kk][nn] = W[(size_t)(k0+kk)*N + n0+nn];
  }
  __syncthreads();
  for (int idx=tid; idx<1024; idx+=256){
    int nn = idx>>5, kk = idx&31;
    float a = tile[kk][nn];
    ushort_t h, l; split2(a, h, l);
    size_t off = (size_t)(n0+nn)*K + k0+kk;
    Whi[off] = h; Wlo[off] = l;
  }
}

// ---------------- split-bf16 MFMA GEMM, 128x128 block, BK=32,
// global_load_lds staging, unpadded stride-32 LDS.
// SWZ=1: XCD-aware block swizzle (T1) — verified win for grid-starved
//        2-phase GEMMs (ff2 FETCH 143->57 MB). SWZ=0 for ff1: R5 A/B showed
//        the swizzle REGRESSED ff1 (89->128 us; 16bn x 64bm @4 blocks/CU
//        already gets same-B co-residency from natural dispatch order).
// NBUF=1: m97 single-buffer (2 barriers/step) — for grids with >=4 blocks/CU.
// NBUF=2: simple 2-phase double-buffer (R3 structure, the verified winner):
//         issue next tile's global_load_lds BEFORE current tile's
//         ds_read+MFMA; ONE __syncthreads per step.
//         NOTE R4 lesson: counted-vmcnt/raw-barrier 2-deep REGRESSED here
//         (T4 requires the 8-phase interleave regime; m230/m233).
// flags: 1 = += into outF, 2 = gelu, 4 = split output planes
template<int NBUF, int SWZ>
__global__ __launch_bounds__(256) void k_gemm_mfma(
    const ushort_t* __restrict__ A_hi, const ushort_t* __restrict__ A_lo,
    const ushort_t* __restrict__ Bt_hi, const ushort_t* __restrict__ Bt_lo,
    const float* __restrict__ bias,
    float* __restrict__ outF,
    ushort_t* __restrict__ out_hi, ushort_t* __restrict__ out_lo,
    int M, int N, int K, int flags){
  // layout: [buf][plane][128*32]
  __shared__ ushort_t As[NBUF*2*128*32];
  __shared__ ushort_t Bs[NBUF*2*128*32];
  int tid = threadIdx.x;
  int bn_i, bm_i;
  if constexpr (SWZ){
    // XCD-aware swizzle (bijective when gridDim.y % 8 == 0)
    int nx = gridDim.x, ny = gridDim.y;
    if ((ny & 7) == 0){
      int flat = blockIdx.x + nx*blockIdx.y;
      int xcd = flat & 7, j = flat >> 3;
      bn_i = j % nx;
      bm_i = xcd*(ny>>3) + j/nx;
    } else {
      bn_i = blockIdx.x; bm_i = blockIdx.y;
    }
  } else {
    bn_i = blockIdx.x; bm_i = blockIdx.y;
  }
  int bn = bn_i * 128, bm = bm_i * 128;
  int w = tid>>6, lane = tid&63;
  int wm = w>>1, wn = w&1;
  int lr = lane&15, quad = lane>>4;
  int lrow = lane>>2, lcol = (lane&3)*8;
  v4f acc[4][4];
  #pragma unroll
  for (int mt=0;mt<4;mt++)
    #pragma unroll
    for (int nt=0;nt<4;nt++) acc[mt][nt] = (v4f){0.f,0.f,0.f,0.f};

  v8s fa_h[4], fa_l[4], fb_h[4], fb_l[4];

  auto STAGE = [&](int buf, int k0){
    #pragma unroll
    for (int i=0;i<2;i++){
      int cr = i*64 + w*16 + lrow;               // tile row this lane stages
      int lb = buf*8192 + (i*64 + w*16)*32;      // wave-uniform LDS base (ushorts)
      size_t goA = (size_t)(bm+cr)*K + k0 + lcol;
      size_t goB = (size_t)(bn+cr)*K + k0 + lcol;
      gl16(A_hi + goA, &As[lb]);
      gl16(A_lo + goA, &As[lb + 4096]);
      gl16(Bt_hi + goB, &Bs[lb]);
      gl16(Bt_lo + goB, &Bs[lb + 4096]);
    }
  };
  auto LOADFRAGS = [&](int buf){
    int bo = buf*8192;
    #pragma unroll
    for (int mt=0;mt<4;mt++){
      int ro = (wm*64 + mt*16 + lr)*32 + quad*8;
      fa_h[mt] = *(const v8s*)&As[bo + ro];
      fa_l[mt] = *(const v8s*)&As[bo + 4096 + ro];
    }
    #pragma unroll
    for (int nt=0;nt<4;nt++){
      int ro = (wn*64 + nt*16 + lr)*32 + quad*8;
      fb_h[nt] = *(const v8s*)&Bs[bo + ro];
      fb_l[nt] = *(const v8s*)&Bs[bo + 4096 + ro];
    }
  };
  auto DOMFMA = [&](){
    #pragma unroll
    for (int mt=0;mt<4;mt++)
      #pragma unroll
      for (int nt=0;nt<4;nt++){
        acc[mt][nt] = __builtin_amdgcn_mfma_f32_16x16x32_bf16(fa_h[mt], fb_h[nt], acc[mt][nt], 0,0,0);
        acc[mt][nt] = __builtin_amdgcn_mfma_f32_16x16x32_bf16(fa_h[mt], fb_l[nt], acc[mt][nt], 0,0,0);
        acc[mt][nt] = __builtin_amdgcn_mfma_f32_16x16x32_bf16(fa_l[mt], fb_h[nt], acc[mt][nt], 0,0,0);
      }
  };

  if constexpr (NBUF == 2){
    STAGE(0, 0);
    __syncthreads();                // drain prologue loads
    int cur = 0;
    for (int k0=0; k0<K; k0+=32){
      if (k0+32 < K) STAGE(cur^1, k0+32);   // next tile in flight during MFMA
      LOADFRAGS(cur);
      DOMFMA();
      __syncthreads();              // single barrier per step: drains next-tile loads
      cur ^= 1;
    }
  } else {
    for (int k0=0; k0<K; k0+=32){
      STAGE(0, k0);
      __syncthreads();
      LOADFRAGS(0);
      DOMFMA();
      __syncthreads();
    }
  }

  #pragma unroll
  for (int mt=0;mt<4;mt++){
    #pragma unroll
    for (int nt=0;nt<4;nt++){
      int col = bn + wn*64 + nt*16 + lr;
      float bv = bias ? bias[col] : 0.f;
      #pragma unroll
      for (int r=0;r<4;r++){
        int row = bm + wm*64 + mt*16 + quad*4 + r;
        float v = acc[mt][nt][r] + bv;
        if (flags & 2){
          float x = v;
          float inner = 0.7978845608028654f * (x + 0.044715f*x*x*x);
          // tanh(i) = 1 - 2/(exp(2i)+1), fast-exp form
          float t = 1.0f - 2.0f / (__expf(2.0f*inner) + 1.0f);
          v = 0.5f*x*(1.0f + t);
        }
        size_t off = (size_t)row*N + col;
        if (flags & 4){
          ushort_t h, l; split2(v, h, l);
          out_hi[off] = h; out_lo[off] = l;
        } else if (flags & 1){
          outF[off] += v;
        } else {
          outF[off] = v;
        }
      }
    }
  }
}

// ---------------- LSH bucketing from split qv planes
__global__ __launch_bounds__(256) void k_buckets(const ushort_t* __restrict__ qv_hi,
                                                 const ushort_t* __restrict__ qv_lo,
                                                 const float* __restrict__ rot,
                                                 int* __restrict__ buckets){
  __shared__ float rotS[DH_][32];
  __shared__ float qs[64][68];
  int t0 = blockIdx.x * 64;
  int h  = blockIdx.y;
  int bh = blockIdx.z;
  int b = bh >> 3, head = bh & 7;
  int tid = threadIdx.x;
  for (int idx = tid; idx < DH_*32; idx += 256){
    int d = idx >> 5, j = idx & 31;
    rotS[d][j] = rot[(size_t)d*(NHASH_*32) + h*32 + j];
  }
  for (int idx = tid; idx < 64*DH_; idx += 256){
    int tt = idx >> 6, d = idx & 63;
    size_t off = ((size_t)(b*T_ + t0 + tt))*QV_N + head*DH_ + d;
    qs[tt][d] = bf2f(qv_hi[off]) + bf2f(qv_lo[off]);
  }
  __syncthreads();
  int tt = tid >> 2, lane = tid & 3;
  int j0 = lane * 8;
  float r8[8];
  #pragma unroll
  for (int k=0;k<8;k++) r8[k] = 0.f;
  for (int d=0; d<DH_; d++){
    float q = qs[tt][d];
    #pragma unroll
    for (int k=0;k<8;k++) r8[k] += q * rotS[d][j0+k];
  }
  float best = r8[0]; int bidx = j0;
  #pragma unroll
  for (int k=1;k<8;k++){ if (r8[k] > best){ best = r8[k]; bidx = j0+k; } }
  #pragma unroll
  for (int k=0;k<8;k++){ float v = -r8[k]; if (v > best){ best = v; bidx = 32+j0+k; } }
  #pragma unroll
  for (int x=1; x<=2; x<<=1){
    float ov = __shfl_xor(best, x);
    int   oi = __shfl_xor(bidx, x);
    if (ov > best || (ov == best && oi < bidx)){ best = ov; bidx = oi; }
  }
  if (lane == 0)
    buckets[((size_t)bh*NHASH_ + h)*T_ + t0 + tt] = bidx;
}

// ---------------- stable counting sort per (bh, hash)
__global__ __launch_bounds__(256) void k_sort(const int* __restrict__ buckets,
                                              int* __restrict__ st){
  int blk = blockIdx.x;
  int bh = blk >> 3, h = blk & 7;
  const int* bptr = buckets + ((size_t)bh*NHASH_ + h)*T_;
  __shared__ unsigned char bb[T_];
  __shared__ int cnt[4][NB_];
  __shared__ int offs[NB_];
  int tid = threadIdx.x;
  for (int i = tid; i < T_; i += 256) bb[i] = (unsigned char)bptr[i];
  __syncthreads();
  int q = tid >> 6, j = tid & 63;
  int c0 = 0;
  for (int t = q*1024; t < q*1024 + 1024; t++) c0 += (bb[t]==j) ? 1 : 0;
  cnt[q][j] = c0;
  __syncthreads();
  if (tid == 0){
    int run = 0;
    for (int jj=0; jj<NB_; jj++){
      offs[jj] = run;
      run += cnt[0][jj] + cnt[1][jj] + cnt[2][jj] + cnt[3][jj];
    }
  }
  __syncthreads();
  int off = offs[j];
  for (int qq=0; qq<q; qq++) off += cnt[qq][j];
  size_t base = (size_t)bh*SORTN_ + (size_t)h*T_;
  for (int t = q*1024; t < q*1024 + 1024; t++){
    if (bb[t]==j){ st[base+off] = t; off++; }
  }
}

// ---------------- flash-MFMA LSH attention; inputs pre-split qv planes
// V^T LDS region is XOR-swizzled: element (d, j) lives at d*136 + (j ^ (d&56)).
__global__ __launch_bounds__(256) void k_attn(const ushort_t* __restrict__ qv_hi,
                                              const ushort_t* __restrict__ qv_lo,
                                              const int* __restrict__ st,
                                              float* __restrict__ lse_un,
                                              float* __restrict__ o_un, int bh0){
  __shared__ ushort_t tileh[128*72];
  __shared__ ushort_t tilel[128*72];
  __shared__ float nrm[128];
  __shared__ int spos[128];
  int blk = blockIdx.x;
  int hh = blk >> 9;
  int bh = bh0 + hh;
  int c = blk & (NCH_-1);
  int h = c >> 6;
  int b = bh >> 3, head = bh & 7;
  int cprev = (c + NCH_ - 1) & (NCH_-1);
  int tid = threadIdx.x;
  const int* stb = st + (size_t)bh * SORTN_;
  if (tid < 128){
    int gc = (tid < 64) ? c : cprev;
    spos[tid] = stb[gc*64 + (tid & 63)];
  }
  __syncthreads();
  // stage QK rows (split planes) + row norms (8-lane shuffle reduce, no atomics)
  for (int idx = tid; idx < 128*8; idx += 256){
    int j = idx >> 3, c8 = (idx & 7) * 8;
    size_t off = ((size_t)(b*T_ + spos[j]))*QV_N + head*DH_ + c8;
    uint4 hv = *(const uint4*)(qv_hi + off);
    uint4 lv = *(const uint4*)(qv_lo + off);
    *(uint4*)&tileh[j*72 + c8] = hv;
    *(uint4*)&tilel[j*72 + c8] = lv;
    const uint32 hw[4] = {hv.x,hv.y,hv.z,hv.w};
    const uint32 lw[4] = {lv.x,lv.y,lv.z,lv.w};
    float ss = 0.f;
    #pragma unroll
    for (int e=0;e<4;e++){
      float a0 = bf2f((ushort_t)(hw[e] & 0xffffu)) + bf2f((ushort_t)(lw[e] & 0xffffu));
      float a1 = bf2f((ushort_t)(hw[e] >> 16))     + bf2f((ushort_t)(lw[e] >> 16));
      ss += a0*a0 + a1*a1;
    }
    // the 8 lanes with the same j are consecutive: reduce across them
    ss += __shfl_xor(ss, 1);
    ss += __shfl_xor(ss, 2);
    ss += __shfl_xor(ss, 4);
    if ((tid & 7) == 0) nrm[j] = ss;
  }
  __syncthreads();
  if (tid < 128) nrm[tid] = 1.0f / sqrtf(fmaxf(nrm[tid], 1e-30f));
  int w = tid >> 6, lane = tid & 63;
  int lr = lane & 15, quad = lane >> 4;
  __syncthreads();
  // S = Qraw x Kraw^T
  v4f sacc[8];
  #pragma unroll
  for (int nt=0;nt<8;nt++) sacc[nt] = (v4f){0.f,0.f,0.f,0.f};
  #pragma unroll
  for (int ks=0; ks<2; ks++){
    int ao = (w*16 + lr)*72 + ks*32 + quad*8;
    v8s fah = *(const v8s*)&tileh[ao];
    v8s fal = *(const v8s*)&tilel[ao];
    #pragma unroll
    for (int nt=0; nt<8; nt++){
      int bo = (nt*16 + lr)*72 + ks*32 + quad*8;
      v8s fbh = *(const v8s*)&tileh[bo];
      v8s fbl = *(const v8s*)&tilel[bo];
      sacc[nt] = __builtin_amdgcn_mfma_f32_16x16x32_bf16(fah, fbh, sacc[nt],0,0,0);
      sacc[nt] = __builtin_amdgcn_mfma_f32_16x16x32_bf16(fah, fbl, sacc[nt],0,0,0);
      sacc[nt] = __builtin_amdgcn_mfma_f32_16x16x32_bf16(fal, fbh, sacc[nt],0,0,0);
    }
  }
  int q0 = w*16 + quad*4;
  int pq[4];
  #pragma unroll
  for (int r=0;r<4;r++) pq[r] = spos[q0 + r];
  float mrow[4] = {-3e38f,-3e38f,-3e38f,-3e38f};
  #pragma unroll
  for (int nt=0;nt<8;nt++){
    int j = nt*16 + lr;
    float sc = nrm[j] * 0.125f;
    int pk = spos[j];
    #pragma unroll
    for (int r=0;r<4;r++){
      float s = sacc[nt][r] * sc;
      if (pk == pq[r]) s = -5.0e4f;
      sacc[nt][r] = s;
      mrow[r] = fmaxf(mrow[r], s);
    }
  }
  #pragma unroll
  for (int r=0;r<4;r++){
    #pragma unroll
    for (int x=1;x<=8;x<<=1) mrow[r] = fmaxf(mrow[r], __shfl_xor(mrow[r], x));
  }
  float srow[4] = {0.f,0.f,0.f,0.f};
  #pragma unroll
  for (int nt=0;nt<8;nt++){
    #pragma unroll
    for (int r=0;r<4;r++){
      float e = __expf(sacc[nt][r] - mrow[r]);
      sacc[nt][r] = e;
      srow[r] += e;
    }
  }
  #pragma unroll
  for (int r=0;r<4;r++){
    #pragma unroll
    for (int x=1;x<=8;x<<=1) srow[r] += __shfl_xor(srow[r], x);
  }
  size_t obase = ((size_t)(hh*NHASH_ + h))*T_;
  if (lr == 0){
    #pragma unroll
    for (int r=0;r<4;r++)
      lse_un[obase + pq[r]] = mrow[r] + __logf(srow[r]);
  }
  float rs[4];
  #pragma unroll
  for (int r=0;r<4;r++) rs[r] = 1.0f / srow[r];
  __syncthreads();
  // P round-trip (rows 0..63, stride 136; <=2-way bank aliasing, free)
  #pragma unroll
  for (int nt=0;nt<8;nt++){
    #pragma unroll
    for (int r=0;r<4;r++){
      float p = sacc[nt][r] * rs[r];
      ushort_t ph, pl; split2(p, ph, pl);
      int o = (q0 + r)*136 + nt*16 + lr;
      tileh[o] = ph; tilel[o] = pl;
    }
  }
  __syncthreads();
  v8s pah[4], pal[4];
  #pragma unroll
  for (int ks=0; ks<4; ks++){
    int ao = (w*16 + lr)*136 + ks*32 + quad*8;
    pah[ks] = *(const v8s*)&tileh[ao];
    pal[ks] = *(const v8s*)&tilel[ao];
  }
  __syncthreads();
  // stage V transposed (swizzled columns: phys col = j ^ (d&56), d&56 == c8)
  for (int idx = tid; idx < 128*8; idx += 256){
    int j = idx >> 3, c8 = (idx & 7) * 8;
    size_t off = ((size_t)(b*T_ + spos[j]))*QV_N + 512 + head*DH_ + c8;
    uint4 hv = *(const uint4*)(qv_hi + off);
    uint4 lv = *(const uint4*)(qv_lo + off);
    const uint32 hw[4] = {hv.x,hv.y,hv.z,hv.w};
    const uint32 lw[4] = {lv.x,lv.y,lv.z,lv.w};
    int jp = j ^ c8;
    #pragma unroll
    for (int e=0;e<4;e++){
      tileh[(c8+2*e+0)*136 + jp] = (ushort_t)(hw[e] & 0xffffu);
      tileh[(c8+2*e+1)*136 + jp] = (ushort_t)(hw[e] >> 16);
      tilel[(c8+2*e+0)*136 + jp] = (ushort_t)(lw[e] & 0xffffu);
      tilel[(c8+2*e+1)*136 + jp] = (ushort_t)(lw[e] >> 16);
    }
  }
  __syncthreads();
  // O = P x V  (V reads un-swizzle: col ^ (row&56); stays 16B-aligned)
  v4f oacc[4];
  #pragma unroll
  for (int nt=0;nt<4;nt++) oacc[nt] = (v4f){0.f,0.f,0.f,0.f};
  #pragma unroll
  for (int ks=0; ks<4; ks++){
    #pragma unroll
    for (int nt=0; nt<4; nt++){
      int row = nt*16 + lr;
      int bo = row*136 + ((ks*32 + quad*8) ^ (row & 56));
      v8s vbh = *(const v8s*)&tileh[bo];
      v8s vbl = *(const v8s*)&tilel[bo];
      oacc[nt] = __builtin_amdgcn_mfma_f32_16x16x32_bf16(pah[ks], vbh, oacc[nt],0,0,0);
      oacc[nt] = __builtin_amdgcn_mfma_f32_16x16x32_bf16(pah[ks], vbl, oacc[nt],0,0,0);
      oacc[nt] = __builtin_amdgcn_mfma_f32_16x16x32_bf16(pal[ks], vbh, oacc[nt],0,0,0);
    }
  }
  #pragma unroll
  for (int r=0;r<4;r++){
    size_t rowoff = (obase + pq[r])*64;
    #pragma unroll
    for (int nt=0;nt<4;nt++){
      o_un[rowoff + nt*16 + lr] = oacc[nt][r];
    }
  }
}

// ---------------- combine hash rounds (coalesced)
__global__ __launch_bounds__(512) void k_combine(const float* __restrict__ lse_un,
                                                 const float* __restrict__ o_un,
                                                 ushort_t* __restrict__ ctx_hi,
                                                 ushort_t* __restrict__ ctx_lo,
                                                 int row0){
  int row = row0 + blockIdx.x;
  int t = row & (T_-1);
  int head = threadIdx.x >> 6, d = threadIdx.x & 63;
  float l[NHASH_];
  float m = -3.0e38f;
  #pragma unroll
  for (int h=0; h<NHASH_; h++){
    l[h] = lse_un[((size_t)(head*NHASH_ + h))*T_ + t];
    m = fmaxf(m, l[h]);
  }
  float sum = 0.f;
  #pragma unroll
  for (int h=0; h<NHASH_; h++){ l[h] = __expf(l[h]-m); sum += l[h]; }
  float rsv = 1.0f/sum;
  float acc = 0.f;
  #pragma unroll
  for (int h=0; h<NHASH_; h++){
    acc += l[h] * o_un[(((size_t)(head*NHASH_ + h))*T_ + t)*64 + d];
  }
  float o = acc * rsv;
  ushort_t hi, lo; split2(o, hi, lo);
  size_t off = (size_t)row*DIM_ + head*DH_ + d;
  ctx_hi[off] = hi; ctx_lo[off] = lo;
}

// ---------------- final head
__global__ __launch_bounds__(64) void k_final(const float* __restrict__ xn,
                                              const float* __restrict__ Wout,
                                              const float* __restrict__ bout,
                                              float* __restrict__ out){
  int row = blockIdx.x;
  int lane = threadIdx.x;
  const float* xr = xn + (size_t)row*DIM_;
  float p[TAGS_];
  #pragma unroll
  for (int n=0;n<TAGS_;n++) p[n] = 0.f;
  for (int d = lane; d < DIM_; d += 64){
    float x = xr[d];
    const float* wr = Wout + (size_t)d*TAGS_;
    #pragma unroll
    for (int n=0;n<TAGS_;n++) p[n] += x * wr[n];
  }
  #pragma unroll
  for (int n=0;n<TAGS_;n++){
    #pragma unroll
    for (int o=32;o>0;o>>=1) p[n] += __shfl_xor(p[n], o);
  }
  if (lane == 0){
    for (int n=0;n<TAGS_;n++) out[(size_t)row*TAGS_ + n] = p[n] + bout[n];
  }
}

extern "C" void kernel_launch(void* const* d_in, const int* in_sizes, int n_in,
                              void* d_out, int out_size, void* d_ws, size_t ws_size,
                              hipStream_t stream){
  const int* X         = (const int*)d_in[0];
  const float* tok     = (const float*)d_in[1];
  const float* ax1     = (const float*)d_in[2];
  const float* ax2     = (const float*)d_in[3];
  const float* Wqk     = (const float*)d_in[4];
  const float* Wv      = (const float*)d_in[5];
  const float* Wo      = (const float*)d_in[6];
  const float* ln1g    = (const float*)d_in[7];
  const float* ln1b    = (const float*)d_in[8];
  const float* W1      = (const float*)d_in[9];
  const float* b1      = (const float*)d_in[10];
  const float* W2      = (const float*)d_in[11];
  const float* b2      = (const float*)d_in[12];
  const float* ln2g    = (const float*)d_in[13];
  const float* ln2b    = (const float*)d_in[14];
  const float* lnfg    = (const float*)d_in[15];
  const float* lnfb    = (const float*)d_in[16];
  const float* WoutP   = (const float*)d_in[17];
  const float* boutP   = (const float*)d_in[18];
  const float* rot     = (const float*)d_in[19];
  float* out = (float*)d_out;

  size_t NX = (size_t)ROWS_*DIM_;            // 4,194,304
  size_t NS = (size_t)BH_*SORTN_;            // 524,288
  const size_t S3  = (size_t)DIM_*DIM_;      // 262,144
  const size_t SW1 = (size_t)DIM_*FF_;       // 1,048,576
  // per-layer weight arena (ushorts): qvw pair (2*2*S3) + wo pair + w1 pair + w2 pair
  const size_t WL  = 4*S3 + 2*S3 + 2*SW1 + 2*SW1;   // 5,767,168

  float* x1 = (float*)d_ws;
  float* x2 = x1 + NX;
  float* lse_un = x2 + NX;                   // NS floats
  int* buckets = (int*)(lse_un + NS);
  int* st  = buckets + NS;
  ushort_t* act_hi = (ushort_t*)(st + NS);   // [ROWS][512] split ctx/ln planes
  ushort_t* act_lo = act_hi + NX;
  ushort_t* qv_hi = act_lo + NX;             // [ROWS][1024] fused qk|v split planes
  ushort_t* qv_lo = qv_hi + (size_t)ROWS_*QV_N;
  ushort_t* warena = qv_lo + (size_t)ROWS_*QV_N;
  float* o_un = (float*)(warena + 2*WL);     // 64 MiB
  ushort_t* ffh_hi = (ushort_t*)o_un;        // FF hidden planes alias o_un
  ushort_t* ffh_lo = ffh_hi + (size_t)ROWS_*FF_;
  float* fbuf = (float*)o_un;                // final-LN fp32 (after FF dead)

  for (int l=0; l<2; l++){
    ushort_t* wl = warena + (size_t)l*WL;
    ushort_t* qvw_h = wl;                    // [1024][512]: rows 0-511 Wqk^T, 512-1023 Wv^T
    ushort_t* qvw_l = qvw_h + 2*S3;
    ushort_t* wo_h  = qvw_l + 2*S3;  ushort_t* wo_l = wo_h + S3;
    ushort_t* w1_h  = wo_l + S3;     ushort_t* w1_l = w1_h + SW1;
    ushort_t* w2_h  = w1_l + SW1;    ushort_t* w2_l = w2_h + SW1;
    k_splitw<<<dim3(DIM_/32, DIM_/32), 256, 0, stream>>>(Wqk + (size_t)l*S3, qvw_h, qvw_l, DIM_, DIM_);
    k_splitw<<<dim3(DIM_/32, DIM_/32), 256, 0, stream>>>(Wv  + (size_t)l*S3, qvw_h + S3, qvw_l + S3, DIM_, DIM_);
    k_splitw<<<dim3(DIM_/32, DIM_/32), 256, 0, stream>>>(Wo  + (size_t)l*S3, wo_h, wo_l, DIM_, DIM_);
    k_splitw<<<dim3(FF_/32,  DIM_/32), 256, 0, stream>>>(W1  + (size_t)l*SW1, w1_h, w1_l, DIM_, FF_);
    k_splitw<<<dim3(DIM_/32, FF_/32),  256, 0, stream>>>(W2  + (size_t)l*SW1, w2_h, w2_l, FF_, DIM_);
  }

  k_embed<<<ROWS_, 256, 0, stream>>>(X, tok, ax1, ax2, x1, x2);
  for (int l=0; l<2; l++){
    ushort_t* wl = warena + (size_t)l*WL;
    ushort_t* qvw_h = wl;
    ushort_t* qvw_l = qvw_h + 2*S3;
    ushort_t* wo_h  = qvw_l + 2*S3;  ushort_t* wo_l = wo_h + S3;
    ushort_t* w1_h  = wo_l + S3;     ushort_t* w1_l = w1_h + SW1;
    ushort_t* w2_h  = w1_l + SW1;    ushort_t* w2_l = w2_h + SW1;
    const float* rot_l = rot + (size_t)l*DH_*NHASH_*32;

    k_ln<<<ROWS_, 256, 0, stream>>>(x2, nullptr, ln1g + l*DIM_, ln1b + l*DIM_, nullptr, act_hi, act_lo);
    // qv: grid 512 (2/CU) — 2-phase dbuf + XCD swizzle
    k_gemm_mfma<2,1><<<dim3(QV_N/128, ROWS_/128), 256, 0, stream>>>(
        act_hi, act_lo, qvw_h, qvw_l, nullptr, nullptr, qv_hi, qv_lo, ROWS_, QV_N, DIM_, 4);
    k_buckets<<<dim3(T_/64, NHASH_, BH_), 256, 0, stream>>>(qv_hi, qv_lo, rot_l, buckets);
    k_sort<<<BH_*NHASH_, 256, 0, stream>>>(buckets, st);
    k_attn<<<8*NCH_, 256, 0, stream>>>(qv_hi, qv_lo, st, lse_un, o_un, 0);
    k_combine<<<T_, 512, 0, stream>>>(lse_un, o_un, act_hi, act_lo, 0);
    k_attn<<<8*NCH_, 256, 0, stream>>>(qv_hi, qv_lo, st, lse_un, o_un, 8);
    k_combine<<<T_, 512, 0, stream>>>(lse_un, o_un, act_hi, act_lo, T_);
    // wo: grid 256 (1/CU) — 2-phase dbuf + XCD swizzle
    k_gemm_mfma<2,1><<<dim3(DIM_/128, ROWS_/128), 256, 0, stream>>>(
        act_hi, act_lo, wo_h, wo_l, nullptr, x1, nullptr, nullptr, ROWS_, DIM_, DIM_, 1);
    k_ln<<<ROWS_, 256, 0, stream>>>(x1, nullptr, ln2g + l*DIM_, ln2b + l*DIM_, nullptr, act_hi, act_lo);
    // ff1: grid 1024 (4/CU) — single-buffer, NO swizzle (R5 A/B: swizzle
    // regressed this config 89->128 us; natural order already co-schedules
    // same-B blocks)
    k_gemm_mfma<1,0><<<dim3(FF_/128, ROWS_/128), 256, 0, stream>>>(
        act_hi, act_lo, w1_h, w1_l, b1 + l*FF_, nullptr, ffh_hi, ffh_lo, ROWS_, FF_, DIM_, 2|4);
    // ff2: grid 256 (1/CU) — 2-phase dbuf + XCD swizzle
    k_gemm_mfma<2,1><<<dim3(DIM_/128, ROWS_/128), 256, 0, stream>>>(
        ffh_hi, ffh_lo, w2_h, w2_l, b2 + l*DIM_, x2, nullptr, nullptr, ROWS_, DIM_, FF_, 1);
  }
  k_ln<<<ROWS_, 256, 0, stream>>>(x1, x2, lnfg, lnfb, fbuf, nullptr, nullptr);
  k_final<<<ROWS_, 64, 0, stream>>>(fbuf, WoutP, boutP, out);
}

// Round 7
// 1205.279 us; speedup vs baseline: 1.1008x; 1.0279x over previous
//
#include <hip/hip_runtime.h>
#include <math.h>

typedef unsigned short ushort_t;
typedef unsigned int uint32;
typedef __attribute__((ext_vector_type(8))) short v8s;
typedef __attribute__((ext_vector_type(4))) float v4f;

#define B_ 2
#define T_ 4096
#define DIM_ 512
#define H_ 8
#define DH_ 64
#define BH_ 16
#define NHASH_ 8
#define NB_ 64
#define NCH_ 512
#define FF_ 2048
#define TAGS_ 17
#define ROWS_ 8192
#define SORTN_ 32768
#define QV_N 1024

__device__ __forceinline__ float bf2f(ushort_t u){
  return __uint_as_float(((uint32)u) << 16);
}
__device__ __forceinline__ ushort_t f2bf(float f){
  uint32 u = __float_as_uint(f);
  u += 0x7fffu + ((u >> 16) & 1u);
  return (ushort_t)(u >> 16);
}
__device__ __forceinline__ void split2(float a, ushort_t& h, ushort_t& l){
  h = f2bf(a);
  l = f2bf(a - bf2f(h));
}
// async global->LDS, 16B per lane; LDS dest = base + lane*16 (wave-uniform base)
__device__ __forceinline__ void gl16(const ushort_t* g, ushort_t* l){
  __builtin_amdgcn_global_load_lds(
      (const __attribute__((address_space(1))) unsigned int*)g,
      (__attribute__((address_space(3))) unsigned int*)l, 16, 0, 0);
}

// ---------------- embed
__global__ __launch_bounds__(256) void k_embed(const int* __restrict__ X,
                                               const float* __restrict__ tok,
                                               const float* __restrict__ ax1,
                                               const float* __restrict__ ax2,
                                               float* __restrict__ x1, float* __restrict__ x2){
  int row = blockIdx.x;
  int t = row & (T_-1);
  int tokid = X[row];
  size_t base = (size_t)row * DIM_;
  for (int d = threadIdx.x; d < DIM_; d += 256){
    float e = tok[(size_t)tokid*DIM_ + d];
    float p = (d < 256) ? ax1[(t>>6)*256 + d] : ax2[(t&63)*256 + (d-256)];
    float v = e + p;
    x1[base+d] = v; x2[base+d] = v;
  }
}

// ---------------- layernorm; writes fp32 (Yf) or split planes (Yh/Yl)
__global__ __launch_bounds__(256) void k_ln(const float* __restrict__ A, const float* __restrict__ Bb,
                                            const float* __restrict__ g, const float* __restrict__ be,
                                            float* __restrict__ Yf,
                                            ushort_t* __restrict__ Yh, ushort_t* __restrict__ Yl){
  int row = blockIdx.x; int tid = threadIdx.x;
  size_t base = (size_t)row * DIM_;
  float x0 = A[base+tid], x1v = A[base+tid+256];
  if (Bb){ x0 = 0.5f*(x0 + Bb[base+tid]); x1v = 0.5f*(x1v + Bb[base+tid+256]); }
  float s = x0 + x1v, sq = x0*x0 + x1v*x1v;
  for (int o=32;o>0;o>>=1){ s += __shfl_down(s,o); sq += __shfl_down(sq,o); }
  __shared__ float ls[4], lq[4], mm[2];
  if ((tid&63)==0){ ls[tid>>6]=s; lq[tid>>6]=sq; }
  __syncthreads();
  if (tid==0){
    float S=ls[0]+ls[1]+ls[2]+ls[3], Q=lq[0]+lq[1]+lq[2]+lq[3];
    float m = S*(1.0f/DIM_); float var = Q*(1.0f/DIM_) - m*m;
    mm[0]=m; mm[1]=1.0f/sqrtf(var+1e-5f);
  }
  __syncthreads();
  float m=mm[0], r=mm[1];
  float y0 = (x0 -m)*r*g[tid]     + be[tid];
  float y1 = (x1v-m)*r*g[tid+256] + be[tid+256];
  if (Yf){
    Yf[base+tid] = y0; Yf[base+tid+256] = y1;
  } else {
    ushort_t h, l;
    split2(y0, h, l); Yh[base+tid] = h;     Yl[base+tid] = l;
    split2(y1, h, l); Yh[base+tid+256] = h; Yl[base+tid+256] = l;
  }
}

// ---------------- weight pre-split + transpose
__global__ __launch_bounds__(256) void k_splitw(const float* __restrict__ W,
                                                ushort_t* __restrict__ Whi, ushort_t* __restrict__ Wlo,
                                                int K, int N){
  __shared__ float tile[32][33];
  int n0 = blockIdx.x*32, k0 = blockIdx.y*32;
  int tid = threadIdx.x;
  for (int idx=tid; idx<1024; idx+=256){
    int kk = idx>>5, nn = idx&31;
    tile[kk][nn] = W[(size_t)(k0+kk)*N + n0+nn];
  }
  __syncthreads();
  for (int idx=tid; idx<1024; idx+=256){
    int nn = idx>>5, kk = idx&31;
    float a = tile[kk][nn];
    ushort_t h, l; split2(a, h, l);
    size_t off = (size_t)(n0+nn)*K + k0+kk;
    Whi[off] = h; Wlo[off] = l;
  }
}

// ---------------- split-bf16 MFMA GEMM, 128x128 block, BK=32,
// global_load_lds staging, unpadded stride-32 LDS.
// SWZ=1: XCD-aware block swizzle (T1) — for grid-starved GEMMs (ff2 FETCH
//        143->57 MB). SWZ=0 for ff1 (R5 A/B: swizzle regressed 89->128 us).
// NBUF=2: 2-phase double-buffer (R3 winner); NBUF=1: m97 single-buffer.
//        R4 lesson: counted-vmcnt 2-deep REGRESSED at this structure.
// NW: waves per block. NW=8 (512 thr) for the 1-block/CU GEMMs (wo, ff2):
//     2 waves/SIMD provides the intra-SIMD TLP (m114 mechanism) that grid
//     occupancy cannot; each wave owns a 32x64 sub-tile (acc 2x4).
//     NW=4 keeps the 4-wave 64x64-sub-tile layout for multi-block grids.
// flags: 1 = += into outF, 2 = gelu, 4 = split output planes
template<int NBUF, int SWZ, int NW>
__global__ __launch_bounds__(NW*64) void k_gemm_mfma(
    const ushort_t* __restrict__ A_hi, const ushort_t* __restrict__ A_lo,
    const ushort_t* __restrict__ Bt_hi, const ushort_t* __restrict__ Bt_lo,
    const float* __restrict__ bias,
    float* __restrict__ outF,
    ushort_t* __restrict__ out_hi, ushort_t* __restrict__ out_lo,
    int M, int N, int K, int flags){
  constexpr int MT = (NW == 4) ? 4 : 2;      // per-wave 16-row tiles
  constexpr int RITER = (NW == 4) ? 2 : 1;   // staging row-iterations
  // layout: [buf][plane][128*32]
  __shared__ ushort_t As[NBUF*2*128*32];
  __shared__ ushort_t Bs[NBUF*2*128*32];
  int tid = threadIdx.x;
  int bn_i, bm_i;
  if constexpr (SWZ){
    // XCD-aware swizzle (bijective when gridDim.y % 8 == 0)
    int nx = gridDim.x, ny = gridDim.y;
    if ((ny & 7) == 0){
      int flat = blockIdx.x + nx*blockIdx.y;
      int xcd = flat & 7, j = flat >> 3;
      bn_i = j % nx;
      bm_i = xcd*(ny>>3) + j/nx;
    } else {
      bn_i = blockIdx.x; bm_i = blockIdx.y;
    }
  } else {
    bn_i = blockIdx.x; bm_i = blockIdx.y;
  }
  int bn = bn_i * 128, bm = bm_i * 128;
  int w = tid>>6, lane = tid&63;
  int wm = w>>1, wn = w&1;
  int lr = lane&15, quad = lane>>4;
  int lrow = lane>>2, lcol = (lane&3)*8;
  v4f acc[MT][4];
  #pragma unroll
  for (int mt=0;mt<MT;mt++)
    #pragma unroll
    for (int nt=0;nt<4;nt++) acc[mt][nt] = (v4f){0.f,0.f,0.f,0.f};

  v8s fa_h[MT], fa_l[MT], fb_h[4], fb_l[4];

  auto STAGE = [&](int buf, int k0){
    #pragma unroll
    for (int i=0;i<RITER;i++){
      int cr = i*64 + w*16 + lrow;               // tile row this lane stages
      int lb = buf*8192 + (i*64 + w*16)*32;      // wave-uniform LDS base (ushorts)
      size_t goA = (size_t)(bm+cr)*K + k0 + lcol;
      size_t goB = (size_t)(bn+cr)*K + k0 + lcol;
      gl16(A_hi + goA, &As[lb]);
      gl16(A_lo + goA, &As[lb + 4096]);
      gl16(Bt_hi + goB, &Bs[lb]);
      gl16(Bt_lo + goB, &Bs[lb + 4096]);
    }
  };
  auto LOADFRAGS = [&](int buf){
    int bo = buf*8192;
    #pragma unroll
    for (int mt=0;mt<MT;mt++){
      int ro = (wm*(MT*16) + mt*16 + lr)*32 + quad*8;
      fa_h[mt] = *(const v8s*)&As[bo + ro];
      fa_l[mt] = *(const v8s*)&As[bo + 4096 + ro];
    }
    #pragma unroll
    for (int nt=0;nt<4;nt++){
      int ro = (wn*64 + nt*16 + lr)*32 + quad*8;
      fb_h[nt] = *(const v8s*)&Bs[bo + ro];
      fb_l[nt] = *(const v8s*)&Bs[bo + 4096 + ro];
    }
  };
  auto DOMFMA = [&](){
    #pragma unroll
    for (int mt=0;mt<MT;mt++)
      #pragma unroll
      for (int nt=0;nt<4;nt++){
        acc[mt][nt] = __builtin_amdgcn_mfma_f32_16x16x32_bf16(fa_h[mt], fb_h[nt], acc[mt][nt], 0,0,0);
        acc[mt][nt] = __builtin_amdgcn_mfma_f32_16x16x32_bf16(fa_h[mt], fb_l[nt], acc[mt][nt], 0,0,0);
        acc[mt][nt] = __builtin_amdgcn_mfma_f32_16x16x32_bf16(fa_l[mt], fb_h[nt], acc[mt][nt], 0,0,0);
      }
  };

  if constexpr (NBUF == 2){
    STAGE(0, 0);
    __syncthreads();                // drain prologue loads
    int cur = 0;
    for (int k0=0; k0<K; k0+=32){
      if (k0+32 < K) STAGE(cur^1, k0+32);   // next tile in flight during MFMA
      LOADFRAGS(cur);
      DOMFMA();
      __syncthreads();              // single barrier per step: drains next-tile loads
      cur ^= 1;
    }
  } else {
    for (int k0=0; k0<K; k0+=32){
      STAGE(0, k0);
      __syncthreads();
      LOADFRAGS(0);
      DOMFMA();
      __syncthreads();
    }
  }

  #pragma unroll
  for (int mt=0;mt<MT;mt++){
    #pragma unroll
    for (int nt=0;nt<4;nt++){
      int col = bn + wn*64 + nt*16 + lr;
      float bv = bias ? bias[col] : 0.f;
      #pragma unroll
      for (int r=0;r<4;r++){
        int row = bm + wm*(MT*16) + mt*16 + quad*4 + r;
        float v = acc[mt][nt][r] + bv;
        if (flags & 2){
          float x = v;
          float inner = 0.7978845608028654f * (x + 0.044715f*x*x*x);
          // tanh(i) = 1 - 2/(exp(2i)+1), fast-exp form
          float t = 1.0f - 2.0f / (__expf(2.0f*inner) + 1.0f);
          v = 0.5f*x*(1.0f + t);
        }
        size_t off = (size_t)row*N + col;
        if (flags & 4){
          ushort_t h, l; split2(v, h, l);
          out_hi[off] = h; out_lo[off] = l;
        } else if (flags & 1){
          outF[off] += v;
        } else {
          outF[off] = v;
        }
      }
    }
  }
}

// ---------------- LSH bucketing from split qv planes
__global__ __launch_bounds__(256) void k_buckets(const ushort_t* __restrict__ qv_hi,
                                                 const ushort_t* __restrict__ qv_lo,
                                                 const float* __restrict__ rot,
                                                 int* __restrict__ buckets){
  __shared__ float rotS[DH_][32];
  __shared__ float qs[64][68];
  int t0 = blockIdx.x * 64;
  int h  = blockIdx.y;
  int bh = blockIdx.z;
  int b = bh >> 3, head = bh & 7;
  int tid = threadIdx.x;
  for (int idx = tid; idx < DH_*32; idx += 256){
    int d = idx >> 5, j = idx & 31;
    rotS[d][j] = rot[(size_t)d*(NHASH_*32) + h*32 + j];
  }
  for (int idx = tid; idx < 64*DH_; idx += 256){
    int tt = idx >> 6, d = idx & 63;
    size_t off = ((size_t)(b*T_ + t0 + tt))*QV_N + head*DH_ + d;
    qs[tt][d] = bf2f(qv_hi[off]) + bf2f(qv_lo[off]);
  }
  __syncthreads();
  int tt = tid >> 2, lane = tid & 3;
  int j0 = lane * 8;
  float r8[8];
  #pragma unroll
  for (int k=0;k<8;k++) r8[k] = 0.f;
  for (int d=0; d<DH_; d++){
    float q = qs[tt][d];
    #pragma unroll
    for (int k=0;k<8;k++) r8[k] += q * rotS[d][j0+k];
  }
  float best = r8[0]; int bidx = j0;
  #pragma unroll
  for (int k=1;k<8;k++){ if (r8[k] > best){ best = r8[k]; bidx = j0+k; } }
  #pragma unroll
  for (int k=0;k<8;k++){ float v = -r8[k]; if (v > best){ best = v; bidx = 32+j0+k; } }
  #pragma unroll
  for (int x=1; x<=2; x<<=1){
    float ov = __shfl_xor(best, x);
    int   oi = __shfl_xor(bidx, x);
    if (ov > best || (ov == best && oi < bidx)){ best = ov; bidx = oi; }
  }
  if (lane == 0)
    buckets[((size_t)bh*NHASH_ + h)*T_ + t0 + tt] = bidx;
}

// ---------------- stable counting sort per (bh, hash)
__global__ __launch_bounds__(256) void k_sort(const int* __restrict__ buckets,
                                              int* __restrict__ st){
  int blk = blockIdx.x;
  int bh = blk >> 3, h = blk & 7;
  const int* bptr = buckets + ((size_t)bh*NHASH_ + h)*T_;
  __shared__ unsigned char bb[T_];
  __shared__ int cnt[4][NB_];
  __shared__ int offs[NB_];
  int tid = threadIdx.x;
  for (int i = tid; i < T_; i += 256) bb[i] = (unsigned char)bptr[i];
  __syncthreads();
  int q = tid >> 6, j = tid & 63;
  int c0 = 0;
  for (int t = q*1024; t < q*1024 + 1024; t++) c0 += (bb[t]==j) ? 1 : 0;
  cnt[q][j] = c0;
  __syncthreads();
  if (tid == 0){
    int run = 0;
    for (int jj=0; jj<NB_; jj++){
      offs[jj] = run;
      run += cnt[0][jj] + cnt[1][jj] + cnt[2][jj] + cnt[3][jj];
    }
  }
  __syncthreads();
  int off = offs[j];
  for (int qq=0; qq<q; qq++) off += cnt[qq][j];
  size_t base = (size_t)bh*SORTN_ + (size_t)h*T_;
  for (int t = q*1024; t < q*1024 + 1024; t++){
    if (bb[t]==j){ st[base+off] = t; off++; }
  }
}

// ---------------- flash-MFMA LSH attention; inputs pre-split qv planes
// V^T LDS region is XOR-swizzled: element (d, j) lives at d*136 + (j ^ (d&56)).
__global__ __launch_bounds__(256) void k_attn(const ushort_t* __restrict__ qv_hi,
                                              const ushort_t* __restrict__ qv_lo,
                                              const int* __restrict__ st,
                                              float* __restrict__ lse_un,
                                              float* __restrict__ o_un, int bh0){
  __shared__ ushort_t tileh[128*72];
  __shared__ ushort_t tilel[128*72];
  __shared__ float nrm[128];
  __shared__ int spos[128];
  int blk = blockIdx.x;
  int hh = blk >> 9;
  int bh = bh0 + hh;
  int c = blk & (NCH_-1);
  int h = c >> 6;
  int b = bh >> 3, head = bh & 7;
  int cprev = (c + NCH_ - 1) & (NCH_-1);
  int tid = threadIdx.x;
  const int* stb = st + (size_t)bh * SORTN_;
  if (tid < 128){
    int gc = (tid < 64) ? c : cprev;
    spos[tid] = stb[gc*64 + (tid & 63)];
  }
  __syncthreads();
  // stage QK rows (split planes) + row norms (8-lane shuffle reduce, no atomics)
  for (int idx = tid; idx < 128*8; idx += 256){
    int j = idx >> 3, c8 = (idx & 7) * 8;
    size_t off = ((size_t)(b*T_ + spos[j]))*QV_N + head*DH_ + c8;
    uint4 hv = *(const uint4*)(qv_hi + off);
    uint4 lv = *(const uint4*)(qv_lo + off);
    *(uint4*)&tileh[j*72 + c8] = hv;
    *(uint4*)&tilel[j*72 + c8] = lv;
    const uint32 hw[4] = {hv.x,hv.y,hv.z,hv.w};
    const uint32 lw[4] = {lv.x,lv.y,lv.z,lv.w};
    float ss = 0.f;
    #pragma unroll
    for (int e=0;e<4;e++){
      float a0 = bf2f((ushort_t)(hw[e] & 0xffffu)) + bf2f((ushort_t)(lw[e] & 0xffffu));
      float a1 = bf2f((ushort_t)(hw[e] >> 16))     + bf2f((ushort_t)(lw[e] >> 16));
      ss += a0*a0 + a1*a1;
    }
    // the 8 lanes with the same j are consecutive: reduce across them
    ss += __shfl_xor(ss, 1);
    ss += __shfl_xor(ss, 2);
    ss += __shfl_xor(ss, 4);
    if ((tid & 7) == 0) nrm[j] = ss;
  }
  __syncthreads();
  if (tid < 128) nrm[tid] = 1.0f / sqrtf(fmaxf(nrm[tid], 1e-30f));
  int w = tid >> 6, lane = tid & 63;
  int lr = lane & 15, quad = lane >> 4;
  __syncthreads();
  // S = Qraw x Kraw^T
  v4f sacc[8];
  #pragma unroll
  for (int nt=0;nt<8;nt++) sacc[nt] = (v4f){0.f,0.f,0.f,0.f};
  #pragma unroll
  for (int ks=0; ks<2; ks++){
    int ao = (w*16 + lr)*72 + ks*32 + quad*8;
    v8s fah = *(const v8s*)&tileh[ao];
    v8s fal = *(const v8s*)&tilel[ao];
    #pragma unroll
    for (int nt=0; nt<8; nt++){
      int bo = (nt*16 + lr)*72 + ks*32 + quad*8;
      v8s fbh = *(const v8s*)&tileh[bo];
      v8s fbl = *(const v8s*)&tilel[bo];
      sacc[nt] = __builtin_amdgcn_mfma_f32_16x16x32_bf16(fah, fbh, sacc[nt],0,0,0);
      sacc[nt] = __builtin_amdgcn_mfma_f32_16x16x32_bf16(fah, fbl, sacc[nt],0,0,0);
      sacc[nt] = __builtin_amdgcn_mfma_f32_16x16x32_bf16(fal, fbh, sacc[nt],0,0,0);
    }
  }
  int q0 = w*16 + quad*4;
  int pq[4];
  #pragma unroll
  for (int r=0;r<4;r++) pq[r] = spos[q0 + r];
  float mrow[4] = {-3e38f,-3e38f,-3e38f,-3e38f};
  #pragma unroll
  for (int nt=0;nt<8;nt++){
    int j = nt*16 + lr;
    float sc = nrm[j] * 0.125f;
    int pk = spos[j];
    #pragma unroll
    for (int r=0;r<4;r++){
      float s = sacc[nt][r] * sc;
      if (pk == pq[r]) s = -5.0e4f;
      sacc[nt][r] = s;
      mrow[r] = fmaxf(mrow[r], s);
    }
  }
  #pragma unroll
  for (int r=0;r<4;r++){
    #pragma unroll
    for (int x=1;x<=8;x<<=1) mrow[r] = fmaxf(mrow[r], __shfl_xor(mrow[r], x));
  }
  float srow[4] = {0.f,0.f,0.f,0.f};
  #pragma unroll
  for (int nt=0;nt<8;nt++){
    #pragma unroll
    for (int r=0;r<4;r++){
      float e = __expf(sacc[nt][r] - mrow[r]);
      sacc[nt][r] = e;
      srow[r] += e;
    }
  }
  #pragma unroll
  for (int r=0;r<4;r++){
    #pragma unroll
    for (int x=1;x<=8;x<<=1) srow[r] += __shfl_xor(srow[r], x);
  }
  size_t obase = ((size_t)(hh*NHASH_ + h))*T_;
  if (lr == 0){
    #pragma unroll
    for (int r=0;r<4;r++)
      lse_un[obase + pq[r]] = mrow[r] + __logf(srow[r]);
  }
  float rs[4];
  #pragma unroll
  for (int r=0;r<4;r++) rs[r] = 1.0f / srow[r];
  __syncthreads();
  // P round-trip (rows 0..63, stride 136; <=2-way bank aliasing, free)
  #pragma unroll
  for (int nt=0;nt<8;nt++){
    #pragma unroll
    for (int r=0;r<4;r++){
      float p = sacc[nt][r] * rs[r];
      ushort_t ph, pl; split2(p, ph, pl);
      int o = (q0 + r)*136 + nt*16 + lr;
      tileh[o] = ph; tilel[o] = pl;
    }
  }
  __syncthreads();
  v8s pah[4], pal[4];
  #pragma unroll
  for (int ks=0; ks<4; ks++){
    int ao = (w*16 + lr)*136 + ks*32 + quad*8;
    pah[ks] = *(const v8s*)&tileh[ao];
    pal[ks] = *(const v8s*)&tilel[ao];
  }
  __syncthreads();
  // stage V transposed (swizzled columns: phys col = j ^ (d&56), d&56 == c8)
  for (int idx = tid; idx < 128*8; idx += 256){
    int j = idx >> 3, c8 = (idx & 7) * 8;
    size_t off = ((size_t)(b*T_ + spos[j]))*QV_N + 512 + head*DH_ + c8;
    uint4 hv = *(const uint4*)(qv_hi + off);
    uint4 lv = *(const uint4*)(qv_lo + off);
    const uint32 hw[4] = {hv.x,hv.y,hv.z,hv.w};
    const uint32 lw[4] = {lv.x,lv.y,lv.z,lv.w};
    int jp = j ^ c8;
    #pragma unroll
    for (int e=0;e<4;e++){
      tileh[(c8+2*e+0)*136 + jp] = (ushort_t)(hw[e] & 0xffffu);
      tileh[(c8+2*e+1)*136 + jp] = (ushort_t)(hw[e] >> 16);
      tilel[(c8+2*e+0)*136 + jp] = (ushort_t)(lw[e] & 0xffffu);
      tilel[(c8+2*e+1)*136 + jp] = (ushort_t)(lw[e] >> 16);
    }
  }
  __syncthreads();
  // O = P x V  (V reads un-swizzle: col ^ (row&56); stays 16B-aligned)
  v4f oacc[4];
  #pragma unroll
  for (int nt=0;nt<4;nt++) oacc[nt] = (v4f){0.f,0.f,0.f,0.f};
  #pragma unroll
  for (int ks=0; ks<4; ks++){
    #pragma unroll
    for (int nt=0; nt<4; nt++){
      int row = nt*16 + lr;
      int bo = row*136 + ((ks*32 + quad*8) ^ (row & 56));
      v8s vbh = *(const v8s*)&tileh[bo];
      v8s vbl = *(const v8s*)&tilel[bo];
      oacc[nt] = __builtin_amdgcn_mfma_f32_16x16x32_bf16(pah[ks], vbh, oacc[nt],0,0,0);
      oacc[nt] = __builtin_amdgcn_mfma_f32_16x16x32_bf16(pah[ks], vbl, oacc[nt],0,0,0);
      oacc[nt] = __builtin_amdgcn_mfma_f32_16x16x32_bf16(pal[ks], vbh, oacc[nt],0,0,0);
    }
  }
  #pragma unroll
  for (int r=0;r<4;r++){
    size_t rowoff = (obase + pq[r])*64;
    #pragma unroll
    for (int nt=0;nt<4;nt++){
      o_un[rowoff + nt*16 + lr] = oacc[nt][r];
    }
  }
}

// ---------------- combine hash rounds (coalesced)
__global__ __launch_bounds__(512) void k_combine(const float* __restrict__ lse_un,
                                                 const float* __restrict__ o_un,
                                                 ushort_t* __restrict__ ctx_hi,
                                                 ushort_t* __restrict__ ctx_lo,
                                                 int row0){
  int row = row0 + blockIdx.x;
  int t = row & (T_-1);
  int head = threadIdx.x >> 6, d = threadIdx.x & 63;
  float l[NHASH_];
  float m = -3.0e38f;
  #pragma unroll
  for (int h=0; h<NHASH_; h++){
    l[h] = lse_un[((size_t)(head*NHASH_ + h))*T_ + t];
    m = fmaxf(m, l[h]);
  }
  float sum = 0.f;
  #pragma unroll
  for (int h=0; h<NHASH_; h++){ l[h] = __expf(l[h]-m); sum += l[h]; }
  float rsv = 1.0f/sum;
  float acc = 0.f;
  #pragma unroll
  for (int h=0; h<NHASH_; h++){
    acc += l[h] * o_un[(((size_t)(head*NHASH_ + h))*T_ + t)*64 + d];
  }
  float o = acc * rsv;
  ushort_t hi, lo; split2(o, hi, lo);
  size_t off = (size_t)row*DIM_ + head*DH_ + d;
  ctx_hi[off] = hi; ctx_lo[off] = lo;
}

// ---------------- final head
__global__ __launch_bounds__(64) void k_final(const float* __restrict__ xn,
                                              const float* __restrict__ Wout,
                                              const float* __restrict__ bout,
                                              float* __restrict__ out){
  int row = blockIdx.x;
  int lane = threadIdx.x;
  const float* xr = xn + (size_t)row*DIM_;
  float p[TAGS_];
  #pragma unroll
  for (int n=0;n<TAGS_;n++) p[n] = 0.f;
  for (int d = lane; d < DIM_; d += 64){
    float x = xr[d];
    const float* wr = Wout + (size_t)d*TAGS_;
    #pragma unroll
    for (int n=0;n<TAGS_;n++) p[n] += x * wr[n];
  }
  #pragma unroll
  for (int n=0;n<TAGS_;n++){
    #pragma unroll
    for (int o=32;o>0;o>>=1) p[n] += __shfl_xor(p[n], o);
  }
  if (lane == 0){
    for (int n=0;n<TAGS_;n++) out[(size_t)row*TAGS_ + n] = p[n] + bout[n];
  }
}

extern "C" void kernel_launch(void* const* d_in, const int* in_sizes, int n_in,
                              void* d_out, int out_size, void* d_ws, size_t ws_size,
                              hipStream_t stream){
  const int* X         = (const int*)d_in[0];
  const float* tok     = (const float*)d_in[1];
  const float* ax1     = (const float*)d_in[2];
  const float* ax2     = (const float*)d_in[3];
  const float* Wqk     = (const float*)d_in[4];
  const float* Wv      = (const float*)d_in[5];
  const float* Wo      = (const float*)d_in[6];
  const float* ln1g    = (const float*)d_in[7];
  const float* ln1b    = (const float*)d_in[8];
  const float* W1      = (const float*)d_in[9];
  const float* b1      = (const float*)d_in[10];
  const float* W2      = (const float*)d_in[11];
  const float* b2      = (const float*)d_in[12];
  const float* ln2g    = (const float*)d_in[13];
  const float* ln2b    = (const float*)d_in[14];
  const float* lnfg    = (const float*)d_in[15];
  const float* lnfb    = (const float*)d_in[16];
  const float* WoutP   = (const float*)d_in[17];
  const float* boutP   = (const float*)d_in[18];
  const float* rot     = (const float*)d_in[19];
  float* out = (float*)d_out;

  size_t NX = (size_t)ROWS_*DIM_;            // 4,194,304
  size_t NS = (size_t)BH_*SORTN_;            // 524,288
  const size_t S3  = (size_t)DIM_*DIM_;      // 262,144
  const size_t SW1 = (size_t)DIM_*FF_;       // 1,048,576
  // per-layer weight arena (ushorts): qvw pair (2*2*S3) + wo pair + w1 pair + w2 pair
  const size_t WL  = 4*S3 + 2*S3 + 2*SW1 + 2*SW1;   // 5,767,168

  float* x1 = (float*)d_ws;
  float* x2 = x1 + NX;
  float* lse_un = x2 + NX;                   // NS floats
  int* buckets = (int*)(lse_un + NS);
  int* st  = buckets + NS;
  ushort_t* act_hi = (ushort_t*)(st + NS);   // [ROWS][512] split ctx/ln planes
  ushort_t* act_lo = act_hi + NX;
  ushort_t* qv_hi = act_lo + NX;             // [ROWS][1024] fused qk|v split planes
  ushort_t* qv_lo = qv_hi + (size_t)ROWS_*QV_N;
  ushort_t* warena = qv_lo + (size_t)ROWS_*QV_N;
  float* o_un = (float*)(warena + 2*WL);     // 64 MiB
  ushort_t* ffh_hi = (ushort_t*)o_un;        // FF hidden planes alias o_un
  ushort_t* ffh_lo = ffh_hi + (size_t)ROWS_*FF_;
  float* fbuf = (float*)o_un;                // final-LN fp32 (after FF dead)

  for (int l=0; l<2; l++){
    ushort_t* wl = warena + (size_t)l*WL;
    ushort_t* qvw_h = wl;                    // [1024][512]: rows 0-511 Wqk^T, 512-1023 Wv^T
    ushort_t* qvw_l = qvw_h + 2*S3;
    ushort_t* wo_h  = qvw_l + 2*S3;  ushort_t* wo_l = wo_h + S3;
    ushort_t* w1_h  = wo_l + S3;     ushort_t* w1_l = w1_h + SW1;
    ushort_t* w2_h  = w1_l + SW1;    ushort_t* w2_l = w2_h + SW1;
    k_splitw<<<dim3(DIM_/32, DIM_/32), 256, 0, stream>>>(Wqk + (size_t)l*S3, qvw_h, qvw_l, DIM_, DIM_);
    k_splitw<<<dim3(DIM_/32, DIM_/32), 256, 0, stream>>>(Wv  + (size_t)l*S3, qvw_h + S3, qvw_l + S3, DIM_, DIM_);
    k_splitw<<<dim3(DIM_/32, DIM_/32), 256, 0, stream>>>(Wo  + (size_t)l*S3, wo_h, wo_l, DIM_, DIM_);
    k_splitw<<<dim3(FF_/32,  DIM_/32), 256, 0, stream>>>(W1  + (size_t)l*SW1, w1_h, w1_l, DIM_, FF_);
    k_splitw<<<dim3(DIM_/32, FF_/32),  256, 0, stream>>>(W2  + (size_t)l*SW1, w2_h, w2_l, FF_, DIM_);
  }

  k_embed<<<ROWS_, 256, 0, stream>>>(X, tok, ax1, ax2, x1, x2);
  for (int l=0; l<2; l++){
    ushort_t* wl = warena + (size_t)l*WL;
    ushort_t* qvw_h = wl;
    ushort_t* qvw_l = qvw_h + 2*S3;
    ushort_t* wo_h  = qvw_l + 2*S3;  ushort_t* wo_l = wo_h + S3;
    ushort_t* w1_h  = wo_l + S3;     ushort_t* w1_l = w1_h + SW1;
    ushort_t* w2_h  = w1_l + SW1;    ushort_t* w2_l = w2_h + SW1;
    const float* rot_l = rot + (size_t)l*DH_*NHASH_*32;

    k_ln<<<ROWS_, 256, 0, stream>>>(x2, nullptr, ln1g + l*DIM_, ln1b + l*DIM_, nullptr, act_hi, act_lo);
    // qv: grid 512 (2/CU, 8 waves/CU already) — 4-wave blocks, 2-phase dbuf + swizzle
    k_gemm_mfma<2,1,4><<<dim3(QV_N/128, ROWS_/128), 256, 0, stream>>>(
        act_hi, act_lo, qvw_h, qvw_l, nullptr, nullptr, qv_hi, qv_lo, ROWS_, QV_N, DIM_, 4);
    k_buckets<<<dim3(T_/64, NHASH_, BH_), 256, 0, stream>>>(qv_hi, qv_lo, rot_l, buckets);
    k_sort<<<BH_*NHASH_, 256, 0, stream>>>(buckets, st);
    k_attn<<<8*NCH_, 256, 0, stream>>>(qv_hi, qv_lo, st, lse_un, o_un, 0);
    k_combine<<<T_, 512, 0, stream>>>(lse_un, o_un, act_hi, act_lo, 0);
    k_attn<<<8*NCH_, 256, 0, stream>>>(qv_hi, qv_lo, st, lse_un, o_un, 8);
    k_combine<<<T_, 512, 0, stream>>>(lse_un, o_un, act_hi, act_lo, T_);
    // wo: grid 256 (1/CU) — 8-wave blocks for intra-SIMD TLP + dbuf + swizzle
    k_gemm_mfma<2,1,8><<<dim3(DIM_/128, ROWS_/128), 512, 0, stream>>>(
        act_hi, act_lo, wo_h, wo_l, nullptr, x1, nullptr, nullptr, ROWS_, DIM_, DIM_, 1);
    k_ln<<<ROWS_, 256, 0, stream>>>(x1, nullptr, ln2g + l*DIM_, ln2b + l*DIM_, nullptr, act_hi, act_lo);
    // ff1: grid 1024 (4/CU) — single-buffer, 4 waves, NO swizzle (R5 A/B)
    k_gemm_mfma<1,0,4><<<dim3(FF_/128, ROWS_/128), 256, 0, stream>>>(
        act_hi, act_lo, w1_h, w1_l, b1 + l*FF_, nullptr, ffh_hi, ffh_lo, ROWS_, FF_, DIM_, 2|4);
    // ff2: grid 256 (1/CU) — 8-wave blocks + dbuf + swizzle
    k_gemm_mfma<2,1,8><<<dim3(DIM_/128, ROWS_/128), 512, 0, stream>>>(
        ffh_hi, ffh_lo, w2_h, w2_l, b2 + l*DIM_, x2, nullptr, nullptr, ROWS_, DIM_, FF_, 1);
  }
  k_ln<<<ROWS_, 256, 0, stream>>>(x1, x2, lnfg, lnfb, fbuf, nullptr, nullptr);
  k_final<<<ROWS_, 64, 0, stream>>>(fbuf, WoutP, boutP, out);
}